// Round 8
// baseline (1532.736 us; speedup 1.0000x reference)
//
#include <hip/hip_runtime.h>
#include <hip/hip_bf16.h>
#include <math.h>

#define PH   264
#define NPIX (PH*PH)          // 69696
#define NBAT 16
#define NIMG (NBAT*64)        // 1024
#define NLAY 4

typedef unsigned short ushort_t;
typedef unsigned int   uint_t;
typedef __attribute__((ext_vector_type(8))) short short8;   // 8 bf16 = 4 VGPR (MFMA A/B frag)
typedef __attribute__((ext_vector_type(4))) float float4v;  // MFMA C/D frag

__device__ __forceinline__ float blo(uint_t u){ union{uint_t u; float f;} v; v.u = u << 16;        return v.f; }
__device__ __forceinline__ float bhi(uint_t u){ union{uint_t u; float f;} v; v.u = u & 0xffff0000u; return v.f; }
__device__ __forceinline__ float b2f(ushort_t s){ union{uint_t u; float f;} v; v.u = ((uint_t)s) << 16; return v.f; }
__device__ __forceinline__ ushort_t f2b(float f){
  __hip_bfloat16 h = __float2bfloat16(f);
  union{__hip_bfloat16 h; ushort_t s;} v; v.h = h; return v.s;
}
// fast erf (A&S 7.1.26, |err|<1.5e-7) -> gelu, rcp + copysign variants (cheap VALU)
__device__ __forceinline__ float gelu_f(float v){
  float x  = v*0.70710678118654752f;
  float ax = fabsf(x);
  float t  = __builtin_amdgcn_rcpf(1.0f + 0.3275911f*ax);
  float poly = t*(0.254829592f + t*(-0.284496736f + t*(1.421413741f + t*(-1.453152027f + t*1.061405429f))));
  float er = 1.0f - poly*__expf(-ax*ax);
  er = copysignf(er, x);
  return 0.5f*v*(1.0f + er);
}

// DFT twiddle tables (fp32, exact integer-mod phase) + bf16 hi/lo inv-y twiddle TWg[272][32]
// + bf16 conv weights cwB[L][o][i] (one-time convert; same rounding as per-layer f2b before).
__global__ __launch_bounds__(256) void k_tables(float* __restrict__ tFT, float* __restrict__ tCT,
                                                float* __restrict__ tST,
                                                ushort_t* __restrict__ TWh, ushort_t* __restrict__ TWl,
                                                const float* __restrict__ cw, ushort_t* __restrict__ cwB){
  int idx = blockIdx.x*256 + threadIdx.x;
  const double W0 = 6.283185307179586 / 264.0;
  if (idx < 8448){                       // tFT[y*32+kk]: kk=2k -> cos, 2k+1 -> -sin (e^{-i 2pi k y/264})
    int y = idx >> 5, kk = idx & 31, k = kk >> 1;
    int ph = (k*y) % 264;
    float ang = (float)(W0 * ph), s, c;
    sincosf(ang, &s, &c);
    tFT[idx] = (kk & 1) ? -s : c;
  } else if (idx < 16896){               // tCT/tST[x*32+kxi]: cos/sin(2pi kxe x/264), kxe in [-16,15]
    int d = idx - 8448;
    int x = d >> 5, kxi = d & 31;
    int kxe = (kxi < 16) ? kxi : kxi - 32;
    int ph = ((kxe*x) % 264 + 264) % 264;
    float ang = (float)(W0 * ph), s, c;
    sincosf(ang, &s, &c);
    tCT[d] = c; tST[d] = s;
  } else if (idx < 16896 + 8704){        // TWg[y][kk]: inv-y row; rows >=264 zero (padding m-tile)
    int d = idx - 16896;
    int y = d >> 5, kk = d & 31;
    float v = 0.f;
    if (y < 264){
      if (kk == 0) v = 0.5f;
      else if (kk > 1){
        int j = kk >> 1;
        int ph = (j*y) % 264;
        float ang = (float)(W0 * ph), s, c;
        sincosf(ang, &s, &c);
        v = (kk & 1) ? -s : c;
      }
    }
    ushort_t hi = f2b(v);
    TWh[d] = hi;
    TWl[d] = f2b(v - b2f(hi));
  } else if (idx < 25600 + 16384){       // cwB: all 4 layers, bf16
    int d = idx - 25600;
    cwB[d] = f2b(cw[d]);
  }
}

// lift + zero-pad; H pixel-major [b][px][c] bf16.
// Vectorized 8x: thread t handles pixel px=bx*32+(t>>3), channels c0..c0+7, one uint4 store
// (was: 1 thread/channel, scalar 2B stores, 71M threads -> issue-bound at 1.35 TB/s, 118us).
__global__ __launch_bounds__(256) void k_lift(const float* __restrict__ xin, const float* __restrict__ lw,
                                              const float* __restrict__ lb, ushort_t* __restrict__ H){
  int t = threadIdx.x, b = blockIdx.y;
  int px = blockIdx.x*32 + (t>>3);
  int c0 = (t&7)*8;
  int x = px / PH, y = px - x*PH;
  bool in = (x < 256 && y < 256);
  float v = in ? xin[((size_t)(b*256+x))*256 + y] : 0.f;
  uint_t w[4];
#pragma unroll
  for (int j=0;j<4;++j){
    float a  = in ? (lw[c0+2*j  ]*v + lb[c0+2*j  ]) : 0.f;
    float bb = in ? (lw[c0+2*j+1]*v + lb[c0+2*j+1]) : 0.f;
    w[j] = (uint_t)f2b(a) | ((uint_t)f2b(bb) << 16);
  }
  *(uint4*)(H + ((size_t)b*NPIX + px)*64 + c0) = *(uint4*)w;
}

// fwd DFT along y: tmp[b][x][kk][c] = sum_y H[b][x*264+y][c] * tFT[y][kk]
__global__ __launch_bounds__(256) void k_fwd_y(const ushort_t* __restrict__ H, const float* __restrict__ tFT,
                                               float* __restrict__ tmp){
  int t = threadIdx.x;
  int row = blockIdx.x*4 + (t>>6);        // 0..4223 = b*264+x
  int c = t & 63;
  int b = row / 264, x = row - b*264;
  const ushort_t* hp = H + ((size_t)b*NPIX + (size_t)x*PH)*64 + c;
  float acc[32];
#pragma unroll
  for (int j=0;j<32;++j) acc[j]=0.f;
  for (int y=0; y<PH; ++y){
    float h = b2f(hp[(size_t)y*64]);
    const float* fr = tFT + y*32;         // wave-uniform
#pragma unroll
    for (int j=0;j<32;++j) acc[j] += h*fr[j];
  }
  float* op = tmp + (((size_t)row)*32)*64 + c;
#pragma unroll
  for (int j=0;j<32;++j) op[(size_t)j*64] = acc[j];
}

// fwd DFT along x: Xf[img=(b*64+c)][m] = sum_x tmp[b][x][ky-pair][c] * e^{-i..}
__global__ __launch_bounds__(256) void k_fwd_x(const float* __restrict__ tmp, const float* __restrict__ tCT,
                                               const float* __restrict__ tST, float* __restrict__ Xf){
  int t = threadIdx.x, b = blockIdx.y;
  int m = blockIdx.x*4 + (t>>6);          // 0..511
  int c = t & 63;
  int kxi = m >> 4, ky = m & 15;
  float xr=0.f, xi=0.f;
  const float* base = tmp + ((size_t)b*264*32 + 2*ky)*64 + c;
  for (int x=0; x<PH; ++x){
    float tr = base[(size_t)x*32*64];
    float ti = base[(size_t)x*32*64 + 64];
    float cc = tCT[x*32+kxi], ss = tST[x*32+kxi];   // wave-uniform
    xr += tr*cc + ti*ss;
    xi += ti*cc - tr*ss;
  }
  ((float2*)Xf)[(size_t)(b*64+c)*512 + m] = make_float2(xr, xi);
}

// per-mode 64x64 complex channel mix (unchanged)
__global__ __launch_bounds__(512) void k_mix(const float* __restrict__ Xf, const float* __restrict__ w1,
                                             const float* __restrict__ w2, float* __restrict__ oft){
  int m = threadIdx.x;
  int o = blockIdx.x;
  int b0 = blockIdx.y*4;
  const float2* X = (const float2*)Xf;
  const float2* W = (const float2*)((m < 256) ? w1 : w2);
  int mm = m & 255;
  float2 acc[4];
#pragma unroll
  for (int b=0;b<4;++b) acc[b] = make_float2(0.f,0.f);
  for (int i=0;i<64;++i){
    float2 w = W[(size_t)(i*64+o)*256 + mm];
#pragma unroll
    for (int b=0;b<4;++b){
      float2 x = X[((size_t)((b0+b)*64+i)*512) + m];
      acc[b].x += x.x*w.x - x.y*w.y;
      acc[b].y += x.x*w.y + x.y*w.x;
    }
  }
  float2* O = (float2*)oft;
#pragma unroll
  for (int b=0;b<4;++b) O[((size_t)((b0+b)*64+o)*512) + m] = acc[b];
}

// GroupNorm stats from oft via Parseval (unchanged)
__global__ __launch_bounds__(256) void k_stats_spec(const float* __restrict__ oft, float2* __restrict__ stats){
  __shared__ float sq[256], s1s[256];
  int bg = blockIdx.x, t = threadIdx.x;
  int b = bg >> 2, g = bg & 3;
  const float2* O = (const float2*)oft;
  float q = 0.f, s1 = 0.f;
  for (int c16=0; c16<16; ++c16){
    const float2* Op = O + (size_t)(b*64 + g*16 + c16)*512;
    for (int m=t; m<512; m+=256){
      if (m & 15){ float2 v = Op[m]; q += 2.f*(v.x*v.x + v.y*v.y); }
    }
  }
  {
    int c16 = t >> 4, j = t & 15;
    const float2* Op = O + (size_t)(b*64 + g*16 + c16)*512;
    if (j == 0){
      float2 a0 = Op[0];
      s1 = a0.x;
      q += a0.x*a0.x;
      float2 h16 = Op[16*16];
      q += 0.5f*(h16.x*h16.x + h16.y*h16.y);
    } else {
      float2 a = Op[j*16];
      float2 bb = Op[(32-j)*16];
      float rr = a.x + bb.x, ii = a.y - bb.y;
      q += 0.5f*(rr*rr + ii*ii);
    }
  }
  sq[t] = q; s1s[t] = s1; __syncthreads();
  for (int st_=128; st_>0; st_>>=1){
    if (t < st_){ sq[t] += sq[t+st_]; s1s[t] += s1s[t+st_]; }
    __syncthreads();
  }
  if (t == 0){
    const float invN = 1.0f/1115136.0f;
    float mu  = s1s[0]*invN;
    float ssq = sq[0]*(1.0f/69696.0f);
    float var = fmaxf(ssq*invN - mu*mu, 0.f);
    stats[bg] = make_float2(mu, 1.0f/sqrtf(var + 1e-5f));
  }
}

// inverse DFT along x, emitting MFMA-B-ready hi/lo bf16 planes premultiplied by
// alpha = rstd*gamma*(2/69696):  zB[((b*264+x)*64 + c)*64 + {0..31:hi, 32..63:lo}]
__global__ __launch_bounds__(256) void k_inv_x(const float* __restrict__ oft, const float* __restrict__ tCT,
                                               const float* __restrict__ tST, ushort_t* __restrict__ zB,
                                               const float2* __restrict__ stats, const float* __restrict__ gg){
  __shared__ float sof[1024];
  int t = threadIdx.x, img = blockIdx.x;
  int b = img >> 6, c = img & 63;
  const float* op = oft + (size_t)img*1024;
  for (int d=t; d<1024; d+=256) sof[d] = op[d];
  __syncthreads();
  float al = stats[b*4 + (c>>4)].y * gg[c] * (2.0f/69696.0f);
  for (int x=t; x<264; x+=256){
    float zr[16], zi[16];
#pragma unroll
    for (int k=0;k<16;++k){ zr[k]=0.f; zi[k]=0.f; }
    for (int kxi=0; kxi<32; ++kxi){
      float cc = tCT[x*32+kxi], ss = tST[x*32+kxi];
#pragma unroll
      for (int ky=0; ky<16; ++ky){
        float orr = sof[(kxi*16+ky)*2], oii = sof[(kxi*16+ky)*2 + 1];
        zr[ky] += orr*cc - oii*ss;
        zi[ky] += oii*cc + orr*ss;
      }
    }
    uint_t wh[16], wl[16];
#pragma unroll
    for (int k=0;k<16;++k){
      float a = zr[k]*al, bb2 = zi[k]*al;
      ushort_t ah = f2b(a),  bh = f2b(bb2);
      ushort_t alo = f2b(a - b2f(ah)), blo_ = f2b(bb2 - b2f(bh));
      wh[k] = (uint_t)ah | ((uint_t)bh << 16);
      wl[k] = (uint_t)alo | ((uint_t)blo_ << 16);
    }
    uint4* dst = (uint4*)(zB + ((size_t)((size_t)(b*264 + x)*64 + c))*64);
#pragma unroll
    for (int q=0;q<4;++q) dst[q]   = ((uint4*)wh)[q];
#pragma unroll
    for (int q=0;q<4;++q) dst[4+q] = ((uint4*)wl)[q];
  }
}

// Row-tile MFMA fused layer: H(new) = gelu( TW·(z·alpha) + H·Wconv + beta ), in place on H.
// grid (264 x-rows, 16 b); 512 thr = 8 waves; wave w owns m-tiles {w, w+8, (16 if w==0)}.
// B operands (zB hi/lo, cwB) PRECOMPUTED in global and staged to LDS with a pure uint4 copy;
// one barrier; MFMA loop LDS-fed. A(spec)=TWg hi/lo global (L2-hot); A(conv)=H global.
// R3 lesson: min-waves must not squeeze regs below acc footprint (spill). (512,3) budget is safe.
__global__ __launch_bounds__(512, 3) void k_fused2(ushort_t* __restrict__ H,
                                                const ushort_t* __restrict__ zB,
                                                const ushort_t* __restrict__ cwB,
                                                const float* __restrict__ cb,
                                                const float* __restrict__ gg, const float* __restrict__ gb,
                                                const float2* __restrict__ stats,
                                                const ushort_t* __restrict__ TWh, const ushort_t* __restrict__ TWl,
                                                int do_gelu){
  __shared__ short zBs[64*72];               // staged zB row: [o][0..31 hi | 32..63 lo], stride 72
  __shared__ short cws[64*72];               // staged conv weights [o][i], stride 72
  __shared__ short obuf[8][16*72];           // per-wave store bounce [px][c], stride 72
  int t = threadIdx.x, b = blockIdx.y, x = blockIdx.x;
  int w = t >> 6, lane = t & 63;
  int quad = lane >> 4, lcol = lane & 15;

  // stage: one uint4 per thread per buffer (8KB each), stride-64 -> stride-72 repack
  {
    int row = t >> 3, q = t & 7;
    const uint4* zsrc = (const uint4*)(zB + ((size_t)(b*264 + x))*64*64);
    *(uint4*)&zBs[row*72 + q*8] = zsrc[t];
    *(uint4*)&cws[row*72 + q*8] = ((const uint4*)cwB)[t];
  }
  __syncthreads();

  float4v acc[3][4];
#pragma unroll
  for (int si=0;si<3;++si)
#pragma unroll
    for (int n=0;n<4;++n) acc[si][n] = (float4v){0.f,0.f,0.f,0.f};

#pragma unroll
  for (int si=0;si<3;++si){
    int mt = w + 8*si;
    if (mt > 16) break;                       // wave-uniform
    int pxl = mt*16 + lcol;                   // local px (row y) 0..271
    union{uint4 u; short8 s;} a0, a1;
    a0.u = make_uint4(0,0,0,0); a1.u = make_uint4(0,0,0,0);
    if (pxl < PH){
      const ushort_t* hp = H + ((size_t)b*NPIX + (size_t)x*PH + pxl)*64 + quad*8;
      a0.u = *(const uint4*)hp;
      a1.u = *(const uint4*)(hp + 32);
    }
    short8 Th = *(const short8*)(TWh + pxl*32 + quad*8);
    short8 Tl = *(const short8*)(TWl + pxl*32 + quad*8);
#pragma unroll
    for (int n=0;n<4;++n){
      float4v a = acc[si][n];
      short8 Bc0 = *(const short8*)&cws[(n*16+lcol)*72 + quad*8];
      short8 Bc1 = *(const short8*)&cws[(n*16+lcol)*72 + 32 + quad*8];
      a = __builtin_amdgcn_mfma_f32_16x16x32_bf16(a0.s, Bc0, a, 0, 0, 0);
      a = __builtin_amdgcn_mfma_f32_16x16x32_bf16(a1.s, Bc1, a, 0, 0, 0);
      short8 Bzh = *(const short8*)&zBs[(n*16+lcol)*72 + quad*8];
      short8 Bzl = *(const short8*)&zBs[(n*16+lcol)*72 + 32 + quad*8];
      a = __builtin_amdgcn_mfma_f32_16x16x32_bf16(Th, Bzh, a, 0, 0, 0);
      a = __builtin_amdgcn_mfma_f32_16x16x32_bf16(Th, Bzl, a, 0, 0, 0);
      a = __builtin_amdgcn_mfma_f32_16x16x32_bf16(Tl, Bzh, a, 0, 0, 0);
      acc[si][n] = a;
    }
  }

  // epilogue: + (gb - mu*rstd*g + cb), gelu, bounce through per-wave LDS, full-line stores.
  float beta[4];
#pragma unroll
  for (int n=0;n<4;++n){
    int o = n*16 + lcol;
    float2 st = stats[b*4 + n];
    beta[n] = gb[o] - st.x*st.y*gg[o] + cb[o];
  }
  short* ob = &obuf[w][0];
#pragma unroll
  for (int si=0;si<3;++si){
    int mt = w + 8*si;
    if (mt > 16) break;
#pragma unroll
    for (int reg=0; reg<4; ++reg){
      int prow = quad*4 + reg;
#pragma unroll
      for (int n=0;n<4;++n){
        float v = acc[si][n][reg] + beta[n];
        if (do_gelu) v = gelu_f(v);
        ob[prow*72 + n*16 + lcol] = (short)f2b(v);
      }
    }
    asm volatile("s_waitcnt lgkmcnt(0)" ::: "memory");   // wave-local: writes visible to own lanes
#pragma unroll
    for (int p=0;p<2;++p){
      int prow2 = p*8 + (lane>>3);
      int c0 = (lane&7)*8;
      int pxl2 = mt*16 + prow2;
      if (pxl2 < PH){
        uint4 u = *(const uint4*)&ob[prow2*72 + c0];
        *(uint4*)(H + ((size_t)b*NPIX + (size_t)x*PH + pxl2)*64 + c0) = u;
      }
    }
    asm volatile("" ::: "memory");   // keep next si's obuf writes below these reads
  }
}

// decoder: crop -> dec1 -> gelu -> dec2, MFMA version.
__global__ __launch_bounds__(256) void k_dec(const ushort_t* __restrict__ H, const float* __restrict__ w1,
                                             const float* __restrict__ b1, const float* __restrict__ w2,
                                             const float* __restrict__ b2, float* __restrict__ out){
  __shared__ short w1h[64*72], w1l[64*72];   // [o][c] hi/lo, stride 72 (16B aligned rows)
  __shared__ float w2L[64], b1L[64];
  int t = threadIdx.x, x = blockIdx.x, b = blockIdx.y;
  for (int d=t; d<4096; d+=256){
    int o = d>>6, c = d&63;
    float v = w1[o*64+c];
    ushort_t hi = f2b(v);
    w1h[o*72+c] = (short)hi;
    w1l[o*72+c] = (short)f2b(v - b2f(hi));
  }
  if (t < 64){ w2L[t] = w2[t]; b1L[t] = b1[t]; }
  __syncthreads();

  int w = t >> 6, lane = t & 63;
  int quad = lane >> 4, lcol = lane & 15;
  float bias2 = b2[0];

#pragma unroll
  for (int i=0;i<4;++i){
    int mt = w*4 + i;                        // 0..15 -> y = mt*16+lcol, all < 256 (crop)
    int py = mt*16 + lcol;
    const ushort_t* hp = H + ((size_t)b*NPIX + (size_t)x*PH + py)*64 + quad*8;
    union{uint4 u; short8 s;} a0, a1;
    a0.u = *(const uint4*)hp;
    a1.u = *(const uint4*)(hp + 32);

    float4v acc[4];
#pragma unroll
    for (int n=0;n<4;++n) acc[n] = (float4v){0.f,0.f,0.f,0.f};
#pragma unroll
    for (int n=0;n<4;++n){
      float4v a = acc[n];
      short8 Bh0 = *(const short8*)&w1h[(n*16+lcol)*72 + quad*8];
      short8 Bh1 = *(const short8*)&w1h[(n*16+lcol)*72 + 32 + quad*8];
      short8 Bl0 = *(const short8*)&w1l[(n*16+lcol)*72 + quad*8];
      short8 Bl1 = *(const short8*)&w1l[(n*16+lcol)*72 + 32 + quad*8];
      a = __builtin_amdgcn_mfma_f32_16x16x32_bf16(a0.s, Bh0, a, 0, 0, 0);
      a = __builtin_amdgcn_mfma_f32_16x16x32_bf16(a1.s, Bh1, a, 0, 0, 0);
      a = __builtin_amdgcn_mfma_f32_16x16x32_bf16(a0.s, Bl0, a, 0, 0, 0);
      a = __builtin_amdgcn_mfma_f32_16x16x32_bf16(a1.s, Bl1, a, 0, 0, 0);
      acc[n] = a;
    }

    float s0=0.f, s1=0.f, s2=0.f, s3=0.f;
#pragma unroll
    for (int n=0;n<4;++n){
      int o = n*16 + lcol;
      float wv = w2L[o];
      float bb = b1L[o];
      s0 += wv*gelu_f(acc[n][0] + bb);
      s1 += wv*gelu_f(acc[n][1] + bb);
      s2 += wv*gelu_f(acc[n][2] + bb);
      s3 += wv*gelu_f(acc[n][3] + bb);
    }
#pragma unroll
    for (int m=1;m<16;m<<=1){
      s0 += __shfl_xor(s0, m, 64);
      s1 += __shfl_xor(s1, m, 64);
      s2 += __shfl_xor(s2, m, 64);
      s3 += __shfl_xor(s3, m, 64);
    }
    if (lcol < 4){
      float v = (lcol==0) ? s0 : (lcol==1) ? s1 : (lcol==2) ? s2 : s3;
      out[((size_t)b*256 + x)*256 + mt*16 + quad*4 + lcol] = v + bias2;
    }
  }
}

extern "C" void kernel_launch(void* const* d_in, const int* in_sizes, int n_in,
                              void* d_out, int out_size, void* d_ws, size_t ws_size,
                              hipStream_t stream){
  const float* x    = (const float*)d_in[0];
  const float* liw  = (const float*)d_in[1];
  const float* lib  = (const float*)d_in[2];
  const float* w1   = (const float*)d_in[3];
  const float* w2   = (const float*)d_in[4];
  const float* cw   = (const float*)d_in[5];
  const float* cb   = (const float*)d_in[6];
  const float* gg   = (const float*)d_in[7];
  const float* gb   = (const float*)d_in[8];
  const float* dw1  = (const float*)d_in[9];
  const float* db1  = (const float*)d_in[10];
  const float* dw2  = (const float*)d_in[11];
  const float* db2  = (const float*)d_in[12];
  float* out = (float*)d_out;

  // ws: H 142.7MB bf16 | tmp 138MB f32 | zB 34.6MB bf16-hi/lo | Xf 4.2MB | oft 4.2MB | tables
  char* p = (char*)d_ws;
  ushort_t* H = (ushort_t*)p; p += (size_t)NBAT*NPIX*64*2;
  float* tmp  = (float*)p; p += (size_t)NBAT*264*32*64*4;
  ushort_t* zB = (ushort_t*)p; p += (size_t)NBAT*264*64*64*2;
  float* Xf   = (float*)p; p += (size_t)NIMG*512*2*4;
  float* oft  = (float*)p; p += (size_t)NIMG*512*2*4;
  float* tFT  = (float*)p; p += 8448*4;
  float* tCT  = (float*)p; p += 8448*4;
  float* tST  = (float*)p; p += 8448*4;
  ushort_t* TWh = (ushort_t*)p; p += 8704*2;
  ushort_t* TWl = (ushort_t*)p; p += 8704*2;
  ushort_t* cwB = (ushort_t*)p; p += 16384*2;
  float2* stats = (float2*)p; p += 64*8;

  k_tables<<<164, 256, 0, stream>>>(tFT, tCT, tST, TWh, TWl, cw, cwB);
  k_lift<<<dim3(NPIX/32, 16), 256, 0, stream>>>(x, liw, lib, H);

  for (int k=0;k<NLAY;++k){
    k_fwd_y<<<1056, 256, 0, stream>>>(H, tFT, tmp);
    k_fwd_x<<<dim3(128,16), 256, 0, stream>>>(tmp, tCT, tST, Xf);
    k_mix<<<dim3(64,4), 512, 0, stream>>>(Xf, w1 + (size_t)k*2097152, w2 + (size_t)k*2097152, oft);
    k_stats_spec<<<64, 256, 0, stream>>>(oft, stats);
    k_inv_x<<<1024, 256, 0, stream>>>(oft, tCT, tST, zB, stats, gg + (size_t)k*64);
    k_fused2<<<dim3(264,16), 512, 0, stream>>>(H, zB, cwB + (size_t)k*4096, cb + (size_t)k*64,
                                               gg + (size_t)k*64, gb + (size_t)k*64, stats, TWh, TWl, (k<3)?1:0);
  }
  k_dec<<<dim3(256,16), 256, 0, stream>>>(H, dw1, db1, dw2, db2, out);
}

// Round 9
// 1442.054 us; speedup vs baseline: 1.0629x; 1.0629x over previous
//
#include <hip/hip_runtime.h>
#include <hip/hip_bf16.h>
#include <math.h>

#define PH   264
#define NPIX (PH*PH)          // 69696
#define NBAT 16
#define NIMG (NBAT*64)        // 1024
#define NLAY 4

typedef unsigned short ushort_t;
typedef unsigned int   uint_t;
typedef __attribute__((ext_vector_type(8))) short short8;   // 8 bf16 = 4 VGPR (MFMA A/B frag)
typedef __attribute__((ext_vector_type(4))) float float4v;  // MFMA C/D frag

__device__ __forceinline__ float blo(uint_t u){ union{uint_t u; float f;} v; v.u = u << 16;        return v.f; }
__device__ __forceinline__ float bhi(uint_t u){ union{uint_t u; float f;} v; v.u = u & 0xffff0000u; return v.f; }
__device__ __forceinline__ float b2f(ushort_t s){ union{uint_t u; float f;} v; v.u = ((uint_t)s) << 16; return v.f; }
__device__ __forceinline__ ushort_t f2b(float f){
  __hip_bfloat16 h = __float2bfloat16(f);
  union{__hip_bfloat16 h; ushort_t s;} v; v.h = h; return v.s;
}
// fast erf (A&S 7.1.26, |err|<1.5e-7) -> gelu, rcp + copysign variants (cheap VALU)
__device__ __forceinline__ float gelu_f(float v){
  float x  = v*0.70710678118654752f;
  float ax = fabsf(x);
  float t  = __builtin_amdgcn_rcpf(1.0f + 0.3275911f*ax);
  float poly = t*(0.254829592f + t*(-0.284496736f + t*(1.421413741f + t*(-1.453152027f + t*1.061405429f))));
  float er = 1.0f - poly*__expf(-ax*ax);
  er = copysignf(er, x);
  return 0.5f*v*(1.0f + er);
}

// DFT twiddle tables (fp32, exact integer-mod phase) + bf16 hi/lo inv-y twiddle TWg[272][32]
// + bf16 conv weights cwB[L][o][i] (one-time convert; same rounding as per-layer f2b before).
__global__ __launch_bounds__(256) void k_tables(float* __restrict__ tFT, float* __restrict__ tCT,
                                                float* __restrict__ tST,
                                                ushort_t* __restrict__ TWh, ushort_t* __restrict__ TWl,
                                                const float* __restrict__ cw, ushort_t* __restrict__ cwB){
  int idx = blockIdx.x*256 + threadIdx.x;
  const double W0 = 6.283185307179586 / 264.0;
  if (idx < 8448){                       // tFT[y*32+kk]: kk=2k -> cos, 2k+1 -> -sin (e^{-i 2pi k y/264})
    int y = idx >> 5, kk = idx & 31, k = kk >> 1;
    int ph = (k*y) % 264;
    float ang = (float)(W0 * ph), s, c;
    sincosf(ang, &s, &c);
    tFT[idx] = (kk & 1) ? -s : c;
  } else if (idx < 16896){               // tCT/tST[x*32+kxi]: cos/sin(2pi kxe x/264), kxe in [-16,15]
    int d = idx - 8448;
    int x = d >> 5, kxi = d & 31;
    int kxe = (kxi < 16) ? kxi : kxi - 32;
    int ph = ((kxe*x) % 264 + 264) % 264;
    float ang = (float)(W0 * ph), s, c;
    sincosf(ang, &s, &c);
    tCT[d] = c; tST[d] = s;
  } else if (idx < 16896 + 8704){        // TWg[y][kk]: inv-y row; rows >=264 zero (padding m-tile)
    int d = idx - 16896;
    int y = d >> 5, kk = d & 31;
    float v = 0.f;
    if (y < 264){
      if (kk == 0) v = 0.5f;
      else if (kk > 1){
        int j = kk >> 1;
        int ph = (j*y) % 264;
        float ang = (float)(W0 * ph), s, c;
        sincosf(ang, &s, &c);
        v = (kk & 1) ? -s : c;
      }
    }
    ushort_t hi = f2b(v);
    TWh[d] = hi;
    TWl[d] = f2b(v - b2f(hi));
  } else if (idx < 25600 + 16384){       // cwB: all 4 layers, bf16
    int d = idx - 25600;
    cwB[d] = f2b(cw[d]);
  }
}

// fwd DFT along y, LAYER 0: lift computed inline from xin (fp32) — no materialized H read.
// tmp[b][x][kk][c] = sum_{y<256} (lw[c]*xin[b,x,y]+lb[c]) * tFT[y][kk];  rows x>=256 are zero.
__global__ __launch_bounds__(256) void k_fwd_y0(const float* __restrict__ xin, const float* __restrict__ lw,
                                                const float* __restrict__ lb, const float* __restrict__ tFT,
                                                float* __restrict__ tmp){
  int t = threadIdx.x;
  int row = blockIdx.x*4 + (t>>6);        // 0..4223 = b*264+x
  int c = t & 63;
  int b = row / 264, x = row - b*264;
  float acc[32];
#pragma unroll
  for (int j=0;j<32;++j) acc[j]=0.f;
  if (x < 256){
    float lwc = lw[c], lbc = lb[c];
    const float* xp = xin + ((size_t)(b*256+x))*256;
    for (int y=0; y<256; ++y){
      float h = lwc*xp[y] + lbc;          // xp[y] wave-uniform broadcast
      const float* fr = tFT + y*32;
#pragma unroll
      for (int j=0;j<32;++j) acc[j] += h*fr[j];
    }
  }
  float* op = tmp + (((size_t)row)*32)*64 + c;
#pragma unroll
  for (int j=0;j<32;++j) op[(size_t)j*64] = acc[j];
}

// fwd DFT along y (layers 1..3): tmp[b][x][kk][c] = sum_y H[b][x*264+y][c] * tFT[y][kk]
__global__ __launch_bounds__(256) void k_fwd_y(const ushort_t* __restrict__ H, const float* __restrict__ tFT,
                                               float* __restrict__ tmp){
  int t = threadIdx.x;
  int row = blockIdx.x*4 + (t>>6);        // 0..4223 = b*264+x
  int c = t & 63;
  int b = row / 264, x = row - b*264;
  const ushort_t* hp = H + ((size_t)b*NPIX + (size_t)x*PH)*64 + c;
  float acc[32];
#pragma unroll
  for (int j=0;j<32;++j) acc[j]=0.f;
  for (int y=0; y<PH; ++y){
    float h = b2f(hp[(size_t)y*64]);
    const float* fr = tFT + y*32;         // wave-uniform
#pragma unroll
    for (int j=0;j<32;++j) acc[j] += h*fr[j];
  }
  float* op = tmp + (((size_t)row)*32)*64 + c;
#pragma unroll
  for (int j=0;j<32;++j) op[(size_t)j*64] = acc[j];
}

// fwd DFT along x: Xf[img=(b*64+c)][m] = sum_x tmp[b][x][ky-pair][c] * e^{-i..}
__global__ __launch_bounds__(256) void k_fwd_x(const float* __restrict__ tmp, const float* __restrict__ tCT,
                                               const float* __restrict__ tST, float* __restrict__ Xf){
  int t = threadIdx.x, b = blockIdx.y;
  int m = blockIdx.x*4 + (t>>6);          // 0..511
  int c = t & 63;
  int kxi = m >> 4, ky = m & 15;
  float xr=0.f, xi=0.f;
  const float* base = tmp + ((size_t)b*264*32 + 2*ky)*64 + c;
  for (int x=0; x<PH; ++x){
    float tr = base[(size_t)x*32*64];
    float ti = base[(size_t)x*32*64 + 64];
    float cc = tCT[x*32+kxi], ss = tST[x*32+kxi];   // wave-uniform
    xr += tr*cc + ti*ss;
    xi += ti*cc - tr*ss;
  }
  ((float2*)Xf)[(size_t)(b*64+c)*512 + m] = make_float2(xr, xi);
}

// per-mode 64x64 complex channel mix (unchanged)
__global__ __launch_bounds__(512) void k_mix(const float* __restrict__ Xf, const float* __restrict__ w1,
                                             const float* __restrict__ w2, float* __restrict__ oft){
  int m = threadIdx.x;
  int o = blockIdx.x;
  int b0 = blockIdx.y*4;
  const float2* X = (const float2*)Xf;
  const float2* W = (const float2*)((m < 256) ? w1 : w2);
  int mm = m & 255;
  float2 acc[4];
#pragma unroll
  for (int b=0;b<4;++b) acc[b] = make_float2(0.f,0.f);
  for (int i=0;i<64;++i){
    float2 w = W[(size_t)(i*64+o)*256 + mm];
#pragma unroll
    for (int b=0;b<4;++b){
      float2 x = X[((size_t)((b0+b)*64+i)*512) + m];
      acc[b].x += x.x*w.x - x.y*w.y;
      acc[b].y += x.x*w.y + x.y*w.x;
    }
  }
  float2* O = (float2*)oft;
#pragma unroll
  for (int b=0;b<4;++b) O[((size_t)((b0+b)*64+o)*512) + m] = acc[b];
}

// GroupNorm stats from oft via Parseval (unchanged)
__global__ __launch_bounds__(256) void k_stats_spec(const float* __restrict__ oft, float2* __restrict__ stats){
  __shared__ float sq[256], s1s[256];
  int bg = blockIdx.x, t = threadIdx.x;
  int b = bg >> 2, g = bg & 3;
  const float2* O = (const float2*)oft;
  float q = 0.f, s1 = 0.f;
  for (int c16=0; c16<16; ++c16){
    const float2* Op = O + (size_t)(b*64 + g*16 + c16)*512;
    for (int m=t; m<512; m+=256){
      if (m & 15){ float2 v = Op[m]; q += 2.f*(v.x*v.x + v.y*v.y); }
    }
  }
  {
    int c16 = t >> 4, j = t & 15;
    const float2* Op = O + (size_t)(b*64 + g*16 + c16)*512;
    if (j == 0){
      float2 a0 = Op[0];
      s1 = a0.x;
      q += a0.x*a0.x;
      float2 h16 = Op[16*16];
      q += 0.5f*(h16.x*h16.x + h16.y*h16.y);
    } else {
      float2 a = Op[j*16];
      float2 bb = Op[(32-j)*16];
      float rr = a.x + bb.x, ii = a.y - bb.y;
      q += 0.5f*(rr*rr + ii*ii);
    }
  }
  sq[t] = q; s1s[t] = s1; __syncthreads();
  for (int st_=128; st_>0; st_>>=1){
    if (t < st_){ sq[t] += sq[t+st_]; s1s[t] += s1s[t+st_]; }
    __syncthreads();
  }
  if (t == 0){
    const float invN = 1.0f/1115136.0f;
    float mu  = s1s[0]*invN;
    float ssq = sq[0]*(1.0f/69696.0f);
    float var = fmaxf(ssq*invN - mu*mu, 0.f);
    stats[bg] = make_float2(mu, 1.0f/sqrtf(var + 1e-5f));
  }
}

// inverse DFT along x, emitting MFMA-B-ready hi/lo bf16 planes premultiplied by
// alpha = rstd*gamma*(2/69696):  zB[((b*264+x)*64 + c)*64 + {0..31:hi, 32..63:lo}]
__global__ __launch_bounds__(256) void k_inv_x(const float* __restrict__ oft, const float* __restrict__ tCT,
                                               const float* __restrict__ tST, ushort_t* __restrict__ zB,
                                               const float2* __restrict__ stats, const float* __restrict__ gg){
  __shared__ float sof[1024];
  int t = threadIdx.x, img = blockIdx.x;
  int b = img >> 6, c = img & 63;
  const float* op = oft + (size_t)img*1024;
  for (int d=t; d<1024; d+=256) sof[d] = op[d];
  __syncthreads();
  float al = stats[b*4 + (c>>4)].y * gg[c] * (2.0f/69696.0f);
  for (int x=t; x<264; x+=256){
    float zr[16], zi[16];
#pragma unroll
    for (int k=0;k<16;++k){ zr[k]=0.f; zi[k]=0.f; }
    for (int kxi=0; kxi<32; ++kxi){
      float cc = tCT[x*32+kxi], ss = tST[x*32+kxi];
#pragma unroll
      for (int ky=0; ky<16; ++ky){
        float orr = sof[(kxi*16+ky)*2], oii = sof[(kxi*16+ky)*2 + 1];
        zr[ky] += orr*cc - oii*ss;
        zi[ky] += oii*cc + orr*ss;
      }
    }
    uint_t wh[16], wl[16];
#pragma unroll
    for (int k=0;k<16;++k){
      float a = zr[k]*al, bb2 = zi[k]*al;
      ushort_t ah = f2b(a),  bh = f2b(bb2);
      ushort_t alo = f2b(a - b2f(ah)), blo_ = f2b(bb2 - b2f(bh));
      wh[k] = (uint_t)ah | ((uint_t)bh << 16);
      wl[k] = (uint_t)alo | ((uint_t)blo_ << 16);
    }
    uint4* dst = (uint4*)(zB + ((size_t)((size_t)(b*264 + x)*64 + c))*64);
#pragma unroll
    for (int q=0;q<4;++q) dst[q]   = ((uint4*)wh)[q];
#pragma unroll
    for (int q=0;q<4;++q) dst[4+q] = ((uint4*)wl)[q];
  }
}

// Row-tile MFMA fused layer: H(new) = gelu( TW·(z·alpha) + H·Wconv + beta ), in place on H.
// grid (264 x-rows, 16 b); 512 thr = 8 waves; wave w owns m-tiles {w, w+8, (16 if w==0)}.
// B operands (zB hi/lo, cwB) PRECOMPUTED in global and staged to LDS with a pure uint4 copy;
// one barrier; MFMA loop LDS-fed. A(spec)=TWg hi/lo global (L2-hot); A(conv)=H global.
// lay0: A(conv) computed INLINE from xin/lw/lb (lift fused; k_lift kernel deleted — its 139MB
// H write was stuck at ~1 TB/s regardless of store pattern, R7/R8 evidence).
// R3 lesson: min-waves must not squeeze regs below acc footprint (spill). (512,3) budget is safe.
__global__ __launch_bounds__(512, 3) void k_fused2(ushort_t* __restrict__ H,
                                                const ushort_t* __restrict__ zB,
                                                const ushort_t* __restrict__ cwB,
                                                const float* __restrict__ cb,
                                                const float* __restrict__ gg, const float* __restrict__ gb,
                                                const float2* __restrict__ stats,
                                                const ushort_t* __restrict__ TWh, const ushort_t* __restrict__ TWl,
                                                const float* __restrict__ xin, const float* __restrict__ lw,
                                                const float* __restrict__ lb,
                                                int do_gelu, int lay0){
  __shared__ short zBs[64*72];               // staged zB row: [o][0..31 hi | 32..63 lo], stride 72
  __shared__ short cws[64*72];               // staged conv weights [o][i], stride 72
  __shared__ short obuf[8][16*72];           // per-wave store bounce [px][c], stride 72
  __shared__ float lwL[64], lbL[64];
  int t = threadIdx.x, b = blockIdx.y, x = blockIdx.x;
  int w = t >> 6, lane = t & 63;
  int quad = lane >> 4, lcol = lane & 15;

  // stage: one uint4 per thread per buffer (8KB each), stride-64 -> stride-72 repack
  {
    int row = t >> 3, q = t & 7;
    const uint4* zsrc = (const uint4*)(zB + ((size_t)(b*264 + x))*64*64);
    *(uint4*)&zBs[row*72 + q*8] = zsrc[t];
    *(uint4*)&cws[row*72 + q*8] = ((const uint4*)cwB)[t];
  }
  if (t < 64){ lwL[t] = lw[t]; lbL[t] = lb[t]; }
  __syncthreads();

  float4v acc[3][4];
#pragma unroll
  for (int si=0;si<3;++si)
#pragma unroll
    for (int n=0;n<4;++n) acc[si][n] = (float4v){0.f,0.f,0.f,0.f};

#pragma unroll
  for (int si=0;si<3;++si){
    int mt = w + 8*si;
    if (mt > 16) break;                       // wave-uniform
    int pxl = mt*16 + lcol;                   // local px (row y) 0..271
    union{uint4 u; short8 s;} a0, a1;
    a0.u = make_uint4(0,0,0,0); a1.u = make_uint4(0,0,0,0);
    if (lay0){
      bool in = (x < 256) && (pxl < 256);
      float xv = in ? xin[((size_t)(b*256+x))*256 + pxl] : 0.f;
      uint_t wa[8];
#pragma unroll
      for (int j=0;j<4;++j){
        int ch = quad*8 + 2*j;
        float v0 = in ? (lwL[ch  ]*xv + lbL[ch  ]) : 0.f;
        float v1 = in ? (lwL[ch+1]*xv + lbL[ch+1]) : 0.f;
        wa[j] = (uint_t)f2b(v0) | ((uint_t)f2b(v1) << 16);
        float v2 = in ? (lwL[ch+32]*xv + lbL[ch+32]) : 0.f;
        float v3 = in ? (lwL[ch+33]*xv + lbL[ch+33]) : 0.f;
        wa[4+j] = (uint_t)f2b(v2) | ((uint_t)f2b(v3) << 16);
      }
      a0.u = make_uint4(wa[0], wa[1], wa[2], wa[3]);
      a1.u = make_uint4(wa[4], wa[5], wa[6], wa[7]);
    } else if (pxl < PH){
      const ushort_t* hp = H + ((size_t)b*NPIX + (size_t)x*PH + pxl)*64 + quad*8;
      a0.u = *(const uint4*)hp;
      a1.u = *(const uint4*)(hp + 32);
    }
    short8 Th = *(const short8*)(TWh + pxl*32 + quad*8);
    short8 Tl = *(const short8*)(TWl + pxl*32 + quad*8);
#pragma unroll
    for (int n=0;n<4;++n){
      float4v a = acc[si][n];
      short8 Bc0 = *(const short8*)&cws[(n*16+lcol)*72 + quad*8];
      short8 Bc1 = *(const short8*)&cws[(n*16+lcol)*72 + 32 + quad*8];
      a = __builtin_amdgcn_mfma_f32_16x16x32_bf16(a0.s, Bc0, a, 0, 0, 0);
      a = __builtin_amdgcn_mfma_f32_16x16x32_bf16(a1.s, Bc1, a, 0, 0, 0);
      short8 Bzh = *(const short8*)&zBs[(n*16+lcol)*72 + quad*8];
      short8 Bzl = *(const short8*)&zBs[(n*16+lcol)*72 + 32 + quad*8];
      a = __builtin_amdgcn_mfma_f32_16x16x32_bf16(Th, Bzh, a, 0, 0, 0);
      a = __builtin_amdgcn_mfma_f32_16x16x32_bf16(Th, Bzl, a, 0, 0, 0);
      a = __builtin_amdgcn_mfma_f32_16x16x32_bf16(Tl, Bzh, a, 0, 0, 0);
      acc[si][n] = a;
    }
  }

  // epilogue: + (gb - mu*rstd*g + cb), gelu, bounce through per-wave LDS, full-line stores.
  float beta[4];
#pragma unroll
  for (int n=0;n<4;++n){
    int o = n*16 + lcol;
    float2 st = stats[b*4 + n];
    beta[n] = gb[o] - st.x*st.y*gg[o] + cb[o];
  }
  short* ob = &obuf[w][0];
#pragma unroll
  for (int si=0;si<3;++si){
    int mt = w + 8*si;
    if (mt > 16) break;
#pragma unroll
    for (int reg=0; reg<4; ++reg){
      int prow = quad*4 + reg;
#pragma unroll
      for (int n=0;n<4;++n){
        float v = acc[si][n][reg] + beta[n];
        if (do_gelu) v = gelu_f(v);
        ob[prow*72 + n*16 + lcol] = (short)f2b(v);
      }
    }
    asm volatile("s_waitcnt lgkmcnt(0)" ::: "memory");   // wave-local: writes visible to own lanes
#pragma unroll
    for (int p=0;p<2;++p){
      int prow2 = p*8 + (lane>>3);
      int c0 = (lane&7)*8;
      int pxl2 = mt*16 + prow2;
      if (pxl2 < PH){
        uint4 u = *(const uint4*)&ob[prow2*72 + c0];
        *(uint4*)(H + ((size_t)b*NPIX + (size_t)x*PH + pxl2)*64 + c0) = u;
      }
    }
    asm volatile("" ::: "memory");   // keep next si's obuf writes below these reads
  }
}

// decoder: crop -> dec1 -> gelu -> dec2, MFMA version.
__global__ __launch_bounds__(256) void k_dec(const ushort_t* __restrict__ H, const float* __restrict__ w1,
                                             const float* __restrict__ b1, const float* __restrict__ w2,
                                             const float* __restrict__ b2, float* __restrict__ out){
  __shared__ short w1h[64*72], w1l[64*72];   // [o][c] hi/lo, stride 72 (16B aligned rows)
  __shared__ float w2L[64], b1L[64];
  int t = threadIdx.x, x = blockIdx.x, b = blockIdx.y;
  for (int d=t; d<4096; d+=256){
    int o = d>>6, c = d&63;
    float v = w1[o*64+c];
    ushort_t hi = f2b(v);
    w1h[o*72+c] = (short)hi;
    w1l[o*72+c] = (short)f2b(v - b2f(hi));
  }
  if (t < 64){ w2L[t] = w2[t]; b1L[t] = b1[t]; }
  __syncthreads();

  int w = t >> 6, lane = t & 63;
  int quad = lane >> 4, lcol = lane & 15;
  float bias2 = b2[0];

#pragma unroll
  for (int i=0;i<4;++i){
    int mt = w*4 + i;                        // 0..15 -> y = mt*16+lcol, all < 256 (crop)
    int py = mt*16 + lcol;
    const ushort_t* hp = H + ((size_t)b*NPIX + (size_t)x*PH + py)*64 + quad*8;
    union{uint4 u; short8 s;} a0, a1;
    a0.u = *(const uint4*)hp;
    a1.u = *(const uint4*)(hp + 32);

    float4v acc[4];
#pragma unroll
    for (int n=0;n<4;++n) acc[n] = (float4v){0.f,0.f,0.f,0.f};
#pragma unroll
    for (int n=0;n<4;++n){
      float4v a = acc[n];
      short8 Bh0 = *(const short8*)&w1h[(n*16+lcol)*72 + quad*8];
      short8 Bh1 = *(const short8*)&w1h[(n*16+lcol)*72 + 32 + quad*8];
      short8 Bl0 = *(const short8*)&w1l[(n*16+lcol)*72 + quad*8];
      short8 Bl1 = *(const short8*)&w1l[(n*16+lcol)*72 + 32 + quad*8];
      a = __builtin_amdgcn_mfma_f32_16x16x32_bf16(a0.s, Bh0, a, 0, 0, 0);
      a = __builtin_amdgcn_mfma_f32_16x16x32_bf16(a1.s, Bh1, a, 0, 0, 0);
      a = __builtin_amdgcn_mfma_f32_16x16x32_bf16(a0.s, Bl0, a, 0, 0, 0);
      a = __builtin_amdgcn_mfma_f32_16x16x32_bf16(a1.s, Bl1, a, 0, 0, 0);
      acc[n] = a;
    }

    float s0=0.f, s1=0.f, s2=0.f, s3=0.f;
#pragma unroll
    for (int n=0;n<4;++n){
      int o = n*16 + lcol;
      float wv = w2L[o];
      float bb = b1L[o];
      s0 += wv*gelu_f(acc[n][0] + bb);
      s1 += wv*gelu_f(acc[n][1] + bb);
      s2 += wv*gelu_f(acc[n][2] + bb);
      s3 += wv*gelu_f(acc[n][3] + bb);
    }
#pragma unroll
    for (int m=1;m<16;m<<=1){
      s0 += __shfl_xor(s0, m, 64);
      s1 += __shfl_xor(s1, m, 64);
      s2 += __shfl_xor(s2, m, 64);
      s3 += __shfl_xor(s3, m, 64);
    }
    if (lcol < 4){
      float v = (lcol==0) ? s0 : (lcol==1) ? s1 : (lcol==2) ? s2 : s3;
      out[((size_t)b*256 + x)*256 + mt*16 + quad*4 + lcol] = v + bias2;
    }
  }
}

extern "C" void kernel_launch(void* const* d_in, const int* in_sizes, int n_in,
                              void* d_out, int out_size, void* d_ws, size_t ws_size,
                              hipStream_t stream){
  const float* x    = (const float*)d_in[0];
  const float* liw  = (const float*)d_in[1];
  const float* lib  = (const float*)d_in[2];
  const float* w1   = (const float*)d_in[3];
  const float* w2   = (const float*)d_in[4];
  const float* cw   = (const float*)d_in[5];
  const float* cb   = (const float*)d_in[6];
  const float* gg   = (const float*)d_in[7];
  const float* gb   = (const float*)d_in[8];
  const float* dw1  = (const float*)d_in[9];
  const float* db1  = (const float*)d_in[10];
  const float* dw2  = (const float*)d_in[11];
  const float* db2  = (const float*)d_in[12];
  float* out = (float*)d_out;

  // ws: H 142.7MB bf16 | tmp 138MB f32 | zB 34.6MB bf16-hi/lo | Xf 4.2MB | oft 4.2MB | tables
  char* p = (char*)d_ws;
  ushort_t* H = (ushort_t*)p; p += (size_t)NBAT*NPIX*64*2;
  float* tmp  = (float*)p; p += (size_t)NBAT*264*32*64*4;
  ushort_t* zB = (ushort_t*)p; p += (size_t)NBAT*264*64*64*2;
  float* Xf   = (float*)p; p += (size_t)NIMG*512*2*4;
  float* oft  = (float*)p; p += (size_t)NIMG*512*2*4;
  float* tFT  = (float*)p; p += 8448*4;
  float* tCT  = (float*)p; p += 8448*4;
  float* tST  = (float*)p; p += 8448*4;
  ushort_t* TWh = (ushort_t*)p; p += 8704*2;
  ushort_t* TWl = (ushort_t*)p; p += 8704*2;
  ushort_t* cwB = (ushort_t*)p; p += 16384*2;
  float2* stats = (float2*)p; p += 64*8;

  k_tables<<<164, 256, 0, stream>>>(tFT, tCT, tST, TWh, TWl, cw, cwB);

  for (int k=0;k<NLAY;++k){
    if (k == 0)
      k_fwd_y0<<<1056, 256, 0, stream>>>(x, liw, lib, tFT, tmp);
    else
      k_fwd_y<<<1056, 256, 0, stream>>>(H, tFT, tmp);
    k_fwd_x<<<dim3(128,16), 256, 0, stream>>>(tmp, tCT, tST, Xf);
    k_mix<<<dim3(64,4), 512, 0, stream>>>(Xf, w1 + (size_t)k*2097152, w2 + (size_t)k*2097152, oft);
    k_stats_spec<<<64, 256, 0, stream>>>(oft, stats);
    k_inv_x<<<1024, 256, 0, stream>>>(oft, tCT, tST, zB, stats, gg + (size_t)k*64);
    k_fused2<<<dim3(264,16), 512, 0, stream>>>(H, zB, cwB + (size_t)k*4096, cb + (size_t)k*64,
                                               gg + (size_t)k*64, gb + (size_t)k*64, stats, TWh, TWl,
                                               x, liw, lib, (k<3)?1:0, (k==0)?1:0);
  }
  k_dec<<<dim3(256,16), 256, 0, stream>>>(H, dw1, db1, dw2, db2, out);
}

// Round 10
// 1371.907 us; speedup vs baseline: 1.1172x; 1.0511x over previous
//
#include <hip/hip_runtime.h>
#include <hip/hip_bf16.h>
#include <math.h>

#define PH   264
#define NPIX (PH*PH)          // 69696
#define NBAT 16
#define NIMG (NBAT*64)        // 1024
#define NLAY 4

typedef unsigned short ushort_t;
typedef unsigned int   uint_t;
typedef __attribute__((ext_vector_type(8))) short short8;   // 8 bf16 = 4 VGPR (MFMA A/B frag)
typedef __attribute__((ext_vector_type(4))) float float4v;  // MFMA C/D frag

__device__ __forceinline__ float blo(uint_t u){ union{uint_t u; float f;} v; v.u = u << 16;        return v.f; }
__device__ __forceinline__ float bhi(uint_t u){ union{uint_t u; float f;} v; v.u = u & 0xffff0000u; return v.f; }
__device__ __forceinline__ float b2f(ushort_t s){ union{uint_t u; float f;} v; v.u = ((uint_t)s) << 16; return v.f; }
__device__ __forceinline__ ushort_t f2b(float f){
  __hip_bfloat16 h = __float2bfloat16(f);
  union{__hip_bfloat16 h; ushort_t s;} v; v.h = h; return v.s;
}
// fast erf (A&S 7.1.26, |err|<1.5e-7) -> gelu, rcp + copysign variants (cheap VALU)
__device__ __forceinline__ float gelu_f(float v){
  float x  = v*0.70710678118654752f;
  float ax = fabsf(x);
  float t  = __builtin_amdgcn_rcpf(1.0f + 0.3275911f*ax);
  float poly = t*(0.254829592f + t*(-0.284496736f + t*(1.421413741f + t*(-1.453152027f + t*1.061405429f))));
  float er = 1.0f - poly*__expf(-ax*ax);
  er = copysignf(er, x);
  return 0.5f*v*(1.0f + er);
}

// DFT twiddle tables (fp32, exact integer-mod phase) + bf16 hi/lo inv-y twiddle TWg[272][32]
// + bf16 conv weights cwB[L][o][i] (one-time convert; same rounding as per-layer f2b before).
__global__ __launch_bounds__(256) void k_tables(float* __restrict__ tFT, float* __restrict__ tCT,
                                                float* __restrict__ tST,
                                                ushort_t* __restrict__ TWh, ushort_t* __restrict__ TWl,
                                                const float* __restrict__ cw, ushort_t* __restrict__ cwB){
  int idx = blockIdx.x*256 + threadIdx.x;
  const double W0 = 6.283185307179586 / 264.0;
  if (idx < 8448){                       // tFT[y*32+kk]: kk=2k -> cos, 2k+1 -> -sin (e^{-i 2pi k y/264})
    int y = idx >> 5, kk = idx & 31, k = kk >> 1;
    int ph = (k*y) % 264;
    float ang = (float)(W0 * ph), s, c;
    sincosf(ang, &s, &c);
    tFT[idx] = (kk & 1) ? -s : c;
  } else if (idx < 16896){               // tCT/tST[x*32+kxi]: cos/sin(2pi kxe x/264), kxe in [-16,15]
    int d = idx - 8448;
    int x = d >> 5, kxi = d & 31;
    int kxe = (kxi < 16) ? kxi : kxi - 32;
    int ph = ((kxe*x) % 264 + 264) % 264;
    float ang = (float)(W0 * ph), s, c;
    sincosf(ang, &s, &c);
    tCT[d] = c; tST[d] = s;
  } else if (idx < 16896 + 8704){        // TWg[y][kk]: inv-y row; rows >=264 zero (padding m-tile)
    int d = idx - 16896;
    int y = d >> 5, kk = d & 31;
    float v = 0.f;
    if (y < 264){
      if (kk == 0) v = 0.5f;
      else if (kk > 1){
        int j = kk >> 1;
        int ph = (j*y) % 264;
        float ang = (float)(W0 * ph), s, c;
        sincosf(ang, &s, &c);
        v = (kk & 1) ? -s : c;
      }
    }
    ushort_t hi = f2b(v);
    TWh[d] = hi;
    TWl[d] = f2b(v - b2f(hi));
  } else if (idx < 25600 + 16384){       // cwB: all 4 layers, bf16
    int d = idx - 25600;
    cwB[d] = f2b(cw[d]);
  }
}

// fwd DFT along y, LAYER 0: lift computed inline from xin (fp32) — no materialized H read.
// tmp[b][x][kk][c] = sum_{y<256} (lw[c]*xin[b,x,y]+lb[c]) * tFT[y][kk];  rows x>=256 are zero.
__global__ __launch_bounds__(256) void k_fwd_y0(const float* __restrict__ xin, const float* __restrict__ lw,
                                                const float* __restrict__ lb, const float* __restrict__ tFT,
                                                float* __restrict__ tmp){
  int t = threadIdx.x;
  int row = blockIdx.x*4 + (t>>6);        // 0..4223 = b*264+x
  int c = t & 63;
  int b = row / 264, x = row - b*264;
  float acc[32];
#pragma unroll
  for (int j=0;j<32;++j) acc[j]=0.f;
  if (x < 256){
    float lwc = lw[c], lbc = lb[c];
    const float* xp = xin + ((size_t)(b*256+x))*256;
    for (int y=0; y<256; ++y){
      float h = lwc*xp[y] + lbc;          // xp[y] wave-uniform broadcast
      const float* fr = tFT + y*32;
#pragma unroll
      for (int j=0;j<32;++j) acc[j] += h*fr[j];
    }
  }
  float* op = tmp + (((size_t)row)*32)*64 + c;
#pragma unroll
  for (int j=0;j<32;++j) op[(size_t)j*64] = acc[j];
}

// fwd DFT along y (layers 1..3): tmp[b][x][kk][c] = sum_y H[b][x*264+y][c] * tFT[y][kk]
__global__ __launch_bounds__(256) void k_fwd_y(const ushort_t* __restrict__ H, const float* __restrict__ tFT,
                                               float* __restrict__ tmp){
  int t = threadIdx.x;
  int row = blockIdx.x*4 + (t>>6);        // 0..4223 = b*264+x
  int c = t & 63;
  int b = row / 264, x = row - b*264;
  const ushort_t* hp = H + ((size_t)b*NPIX + (size_t)x*PH)*64 + c;
  float acc[32];
#pragma unroll
  for (int j=0;j<32;++j) acc[j]=0.f;
  for (int y=0; y<PH; ++y){
    float h = b2f(hp[(size_t)y*64]);
    const float* fr = tFT + y*32;         // wave-uniform
#pragma unroll
    for (int j=0;j<32;++j) acc[j] += h*fr[j];
  }
  float* op = tmp + (((size_t)row)*32)*64 + c;
#pragma unroll
  for (int j=0;j<32;++j) op[(size_t)j*64] = acc[j];
}

// fwd DFT along x: Xf[img=(b*64+c)][m] = sum_x tmp[b][x][ky-pair][c] * e^{-i..}
__global__ __launch_bounds__(256) void k_fwd_x(const float* __restrict__ tmp, const float* __restrict__ tCT,
                                               const float* __restrict__ tST, float* __restrict__ Xf){
  int t = threadIdx.x, b = blockIdx.y;
  int m = blockIdx.x*4 + (t>>6);          // 0..511
  int c = t & 63;
  int kxi = m >> 4, ky = m & 15;
  float xr=0.f, xi=0.f;
  const float* base = tmp + ((size_t)b*264*32 + 2*ky)*64 + c;
  for (int x=0; x<PH; ++x){
    float tr = base[(size_t)x*32*64];
    float ti = base[(size_t)x*32*64 + 64];
    float cc = tCT[x*32+kxi], ss = tST[x*32+kxi];   // wave-uniform
    xr += tr*cc + ti*ss;
    xi += ti*cc - tr*ss;
  }
  ((float2*)Xf)[(size_t)(b*64+c)*512 + m] = make_float2(xr, xi);
}

// per-mode 64x64 complex channel mix (unchanged)
__global__ __launch_bounds__(512) void k_mix(const float* __restrict__ Xf, const float* __restrict__ w1,
                                             const float* __restrict__ w2, float* __restrict__ oft){
  int m = threadIdx.x;
  int o = blockIdx.x;
  int b0 = blockIdx.y*4;
  const float2* X = (const float2*)Xf;
  const float2* W = (const float2*)((m < 256) ? w1 : w2);
  int mm = m & 255;
  float2 acc[4];
#pragma unroll
  for (int b=0;b<4;++b) acc[b] = make_float2(0.f,0.f);
  for (int i=0;i<64;++i){
    float2 w = W[(size_t)(i*64+o)*256 + mm];
#pragma unroll
    for (int b=0;b<4;++b){
      float2 x = X[((size_t)((b0+b)*64+i)*512) + m];
      acc[b].x += x.x*w.x - x.y*w.y;
      acc[b].y += x.x*w.y + x.y*w.x;
    }
  }
  float2* O = (float2*)oft;
#pragma unroll
  for (int b=0;b<4;++b) O[((size_t)((b0+b)*64+o)*512) + m] = acc[b];
}

// GroupNorm stats from oft via Parseval (unchanged)
__global__ __launch_bounds__(256) void k_stats_spec(const float* __restrict__ oft, float2* __restrict__ stats){
  __shared__ float sq[256], s1s[256];
  int bg = blockIdx.x, t = threadIdx.x;
  int b = bg >> 2, g = bg & 3;
  const float2* O = (const float2*)oft;
  float q = 0.f, s1 = 0.f;
  for (int c16=0; c16<16; ++c16){
    const float2* Op = O + (size_t)(b*64 + g*16 + c16)*512;
    for (int m=t; m<512; m+=256){
      if (m & 15){ float2 v = Op[m]; q += 2.f*(v.x*v.x + v.y*v.y); }
    }
  }
  {
    int c16 = t >> 4, j = t & 15;
    const float2* Op = O + (size_t)(b*64 + g*16 + c16)*512;
    if (j == 0){
      float2 a0 = Op[0];
      s1 = a0.x;
      q += a0.x*a0.x;
      float2 h16 = Op[16*16];
      q += 0.5f*(h16.x*h16.x + h16.y*h16.y);
    } else {
      float2 a = Op[j*16];
      float2 bb = Op[(32-j)*16];
      float rr = a.x + bb.x, ii = a.y - bb.y;
      q += 0.5f*(rr*rr + ii*ii);
    }
  }
  sq[t] = q; s1s[t] = s1; __syncthreads();
  for (int st_=128; st_>0; st_>>=1){
    if (t < st_){ sq[t] += sq[t+st_]; s1s[t] += s1s[t+st_]; }
    __syncthreads();
  }
  if (t == 0){
    const float invN = 1.0f/1115136.0f;
    float mu  = s1s[0]*invN;
    float ssq = sq[0]*(1.0f/69696.0f);
    float var = fmaxf(ssq*invN - mu*mu, 0.f);
    stats[bg] = make_float2(mu, 1.0f/sqrtf(var + 1e-5f));
  }
}

// inverse DFT along x, emitting MFMA-B-ready hi/lo bf16 planes premultiplied by
// alpha = rstd*gamma*(2/69696):  zB[((b*264+x)*64 + c)*64 + {0..31:hi, 32..63:lo}]
__global__ __launch_bounds__(256) void k_inv_x(const float* __restrict__ oft, const float* __restrict__ tCT,
                                               const float* __restrict__ tST, ushort_t* __restrict__ zB,
                                               const float2* __restrict__ stats, const float* __restrict__ gg){
  __shared__ float sof[1024];
  int t = threadIdx.x, img = blockIdx.x;
  int b = img >> 6, c = img & 63;
  const float* op = oft + (size_t)img*1024;
  for (int d=t; d<1024; d+=256) sof[d] = op[d];
  __syncthreads();
  float al = stats[b*4 + (c>>4)].y * gg[c] * (2.0f/69696.0f);
  for (int x=t; x<264; x+=256){
    float zr[16], zi[16];
#pragma unroll
    for (int k=0;k<16;++k){ zr[k]=0.f; zi[k]=0.f; }
    for (int kxi=0; kxi<32; ++kxi){
      float cc = tCT[x*32+kxi], ss = tST[x*32+kxi];
#pragma unroll
      for (int ky=0; ky<16; ++ky){
        float orr = sof[(kxi*16+ky)*2], oii = sof[(kxi*16+ky)*2 + 1];
        zr[ky] += orr*cc - oii*ss;
        zi[ky] += oii*cc + orr*ss;
      }
    }
    uint_t wh[16], wl[16];
#pragma unroll
    for (int k=0;k<16;++k){
      float a = zr[k]*al, bb2 = zi[k]*al;
      ushort_t ah = f2b(a),  bh = f2b(bb2);
      ushort_t alo = f2b(a - b2f(ah)), blo_ = f2b(bb2 - b2f(bh));
      wh[k] = (uint_t)ah | ((uint_t)bh << 16);
      wl[k] = (uint_t)alo | ((uint_t)blo_ << 16);
    }
    uint4* dst = (uint4*)(zB + ((size_t)((size_t)(b*264 + x)*64 + c))*64);
#pragma unroll
    for (int q=0;q<4;++q) dst[q]   = ((uint4*)wh)[q];
#pragma unroll
    for (int q=0;q<4;++q) dst[4+q] = ((uint4*)wl)[q];
  }
}

// Row-tile MFMA fused layer: H(new) = gelu( TW·(z·alpha) + H·Wconv + beta ), in place on H.
// grid (264 x-rows, 16 b); 512 thr = 8 waves; wave w owns m-tiles {w, w+8, (16 if w==0)}.
// B operands (zB hi/lo, cwB) PRECOMPUTED in global, staged to LDS (uint4 copy); MFMA LDS-fed.
// lay0: A(conv) computed INLINE from xin/lw/lb (lift fused).
// LDS: obuf ALIASES zBs/cws (dead after MFMA loop, barrier-protected) -> 19KB total, and
// __launch_bounds__(512,4) pins <=128 unified regs (acc 48 AGPR + ~68 VGPR = ~116, 12 slack)
// -> 2 blocks/CU (was 37KB + ~132 regs -> 1 block/CU, Occupancy 19%, latency-bound at 126us).
// R3 lesson: watch for spill signature (VGPR drop + FETCH/WRITE balloon) -> revert bound.
__global__ __launch_bounds__(512, 4) void k_fused2(ushort_t* __restrict__ H,
                                                const ushort_t* __restrict__ zB,
                                                const ushort_t* __restrict__ cwB,
                                                const float* __restrict__ cb,
                                                const float* __restrict__ gg, const float* __restrict__ gb,
                                                const float2* __restrict__ stats,
                                                const ushort_t* __restrict__ TWh, const ushort_t* __restrict__ TWl,
                                                const float* __restrict__ xin, const float* __restrict__ lw,
                                                const float* __restrict__ lb,
                                                int do_gelu, int lay0){
  __shared__ short smem[9216];               // phase1: zBs[0..4607], cws[4608..9215] (stride 72)
                                             // phase2 (after barrier): obuf[w] = smem + w*1152
  __shared__ float lwL[64], lbL[64];
  short* zBs = smem;
  short* cws = smem + 4608;
  int t = threadIdx.x, b = blockIdx.y, x = blockIdx.x;
  int w = t >> 6, lane = t & 63;
  int quad = lane >> 4, lcol = lane & 15;

  // stage: one uint4 per thread per buffer (8KB each), stride-64 -> stride-72 repack
  {
    int row = t >> 3, q = t & 7;
    const uint4* zsrc = (const uint4*)(zB + ((size_t)(b*264 + x))*64*64);
    *(uint4*)&zBs[row*72 + q*8] = zsrc[t];
    *(uint4*)&cws[row*72 + q*8] = ((const uint4*)cwB)[t];
  }
  if (t < 64){ lwL[t] = lw[t]; lbL[t] = lb[t]; }
  __syncthreads();

  float4v acc[3][4];
#pragma unroll
  for (int si=0;si<3;++si)
#pragma unroll
    for (int n=0;n<4;++n) acc[si][n] = (float4v){0.f,0.f,0.f,0.f};

#pragma unroll
  for (int si=0;si<3;++si){
    int mt = w + 8*si;
    if (mt > 16) break;                       // wave-uniform
    int pxl = mt*16 + lcol;                   // local px (row y) 0..271
    union{uint4 u; short8 s;} a0, a1;
    a0.u = make_uint4(0,0,0,0); a1.u = make_uint4(0,0,0,0);
    if (lay0){
      bool in = (x < 256) && (pxl < 256);
      float xv = in ? xin[((size_t)(b*256+x))*256 + pxl] : 0.f;
      uint_t wa[8];
#pragma unroll
      for (int j=0;j<4;++j){
        int ch = quad*8 + 2*j;
        float v0 = in ? (lwL[ch  ]*xv + lbL[ch  ]) : 0.f;
        float v1 = in ? (lwL[ch+1]*xv + lbL[ch+1]) : 0.f;
        wa[j] = (uint_t)f2b(v0) | ((uint_t)f2b(v1) << 16);
        float v2 = in ? (lwL[ch+32]*xv + lbL[ch+32]) : 0.f;
        float v3 = in ? (lwL[ch+33]*xv + lbL[ch+33]) : 0.f;
        wa[4+j] = (uint_t)f2b(v2) | ((uint_t)f2b(v3) << 16);
      }
      a0.u = make_uint4(wa[0], wa[1], wa[2], wa[3]);
      a1.u = make_uint4(wa[4], wa[5], wa[6], wa[7]);
    } else if (pxl < PH){
      const ushort_t* hp = H + ((size_t)b*NPIX + (size_t)x*PH + pxl)*64 + quad*8;
      a0.u = *(const uint4*)hp;
      a1.u = *(const uint4*)(hp + 32);
    }
    short8 Th = *(const short8*)(TWh + pxl*32 + quad*8);
    short8 Tl = *(const short8*)(TWl + pxl*32 + quad*8);
#pragma unroll
    for (int n=0;n<4;++n){
      float4v a = acc[si][n];
      short8 Bc0 = *(const short8*)&cws[(n*16+lcol)*72 + quad*8];
      short8 Bc1 = *(const short8*)&cws[(n*16+lcol)*72 + 32 + quad*8];
      a = __builtin_amdgcn_mfma_f32_16x16x32_bf16(a0.s, Bc0, a, 0, 0, 0);
      a = __builtin_amdgcn_mfma_f32_16x16x32_bf16(a1.s, Bc1, a, 0, 0, 0);
      short8 Bzh = *(const short8*)&zBs[(n*16+lcol)*72 + quad*8];
      short8 Bzl = *(const short8*)&zBs[(n*16+lcol)*72 + 32 + quad*8];
      a = __builtin_amdgcn_mfma_f32_16x16x32_bf16(Th, Bzh, a, 0, 0, 0);
      a = __builtin_amdgcn_mfma_f32_16x16x32_bf16(Th, Bzl, a, 0, 0, 0);
      a = __builtin_amdgcn_mfma_f32_16x16x32_bf16(Tl, Bzh, a, 0, 0, 0);
      acc[si][n] = a;
    }
  }

  __syncthreads();   // zBs/cws dead for ALL waves -> obuf may alias them

  // epilogue: + (gb - mu*rstd*g + cb), gelu, bounce through per-wave LDS, full-line stores.
  float beta[4];
#pragma unroll
  for (int n=0;n<4;++n){
    int o = n*16 + lcol;
    float2 st = stats[b*4 + n];
    beta[n] = gb[o] - st.x*st.y*gg[o] + cb[o];
  }
  short* ob = smem + w*1152;                 // 16 px * stride 72
#pragma unroll
  for (int si=0;si<3;++si){
    int mt = w + 8*si;
    if (mt > 16) break;
#pragma unroll
    for (int reg=0; reg<4; ++reg){
      int prow = quad*4 + reg;
#pragma unroll
      for (int n=0;n<4;++n){
        float v = acc[si][n][reg] + beta[n];
        if (do_gelu) v = gelu_f(v);
        ob[prow*72 + n*16 + lcol] = (short)f2b(v);
      }
    }
    asm volatile("s_waitcnt lgkmcnt(0)" ::: "memory");   // wave-local: writes visible to own lanes
#pragma unroll
    for (int p=0;p<2;++p){
      int prow2 = p*8 + (lane>>3);
      int c0 = (lane&7)*8;
      int pxl2 = mt*16 + prow2;
      if (pxl2 < PH){
        uint4 u = *(const uint4*)&ob[prow2*72 + c0];
        *(uint4*)(H + ((size_t)b*NPIX + (size_t)x*PH + pxl2)*64 + c0) = u;
      }
    }
    asm volatile("" ::: "memory");   // keep next si's obuf writes below these reads
  }
}

// decoder: crop -> dec1 -> gelu -> dec2, MFMA version.
__global__ __launch_bounds__(256) void k_dec(const ushort_t* __restrict__ H, const float* __restrict__ w1,
                                             const float* __restrict__ b1, const float* __restrict__ w2,
                                             const float* __restrict__ b2, float* __restrict__ out){
  __shared__ short w1h[64*72], w1l[64*72];   // [o][c] hi/lo, stride 72 (16B aligned rows)
  __shared__ float w2L[64], b1L[64];
  int t = threadIdx.x, x = blockIdx.x, b = blockIdx.y;
  for (int d=t; d<4096; d+=256){
    int o = d>>6, c = d&63;
    float v = w1[o*64+c];
    ushort_t hi = f2b(v);
    w1h[o*72+c] = (short)hi;
    w1l[o*72+c] = (short)f2b(v - b2f(hi));
  }
  if (t < 64){ w2L[t] = w2[t]; b1L[t] = b1[t]; }
  __syncthreads();

  int w = t >> 6, lane = t & 63;
  int quad = lane >> 4, lcol = lane & 15;
  float bias2 = b2[0];

#pragma unroll
  for (int i=0;i<4;++i){
    int mt = w*4 + i;                        // 0..15 -> y = mt*16+lcol, all < 256 (crop)
    int py = mt*16 + lcol;
    const ushort_t* hp = H + ((size_t)b*NPIX + (size_t)x*PH + py)*64 + quad*8;
    union{uint4 u; short8 s;} a0, a1;
    a0.u = *(const uint4*)hp;
    a1.u = *(const uint4*)(hp + 32);

    float4v acc[4];
#pragma unroll
    for (int n=0;n<4;++n) acc[n] = (float4v){0.f,0.f,0.f,0.f};
#pragma unroll
    for (int n=0;n<4;++n){
      float4v a = acc[n];
      short8 Bh0 = *(const short8*)&w1h[(n*16+lcol)*72 + quad*8];
      short8 Bh1 = *(const short8*)&w1h[(n*16+lcol)*72 + 32 + quad*8];
      short8 Bl0 = *(const short8*)&w1l[(n*16+lcol)*72 + quad*8];
      short8 Bl1 = *(const short8*)&w1l[(n*16+lcol)*72 + 32 + quad*8];
      a = __builtin_amdgcn_mfma_f32_16x16x32_bf16(a0.s, Bh0, a, 0, 0, 0);
      a = __builtin_amdgcn_mfma_f32_16x16x32_bf16(a1.s, Bh1, a, 0, 0, 0);
      a = __builtin_amdgcn_mfma_f32_16x16x32_bf16(a0.s, Bl0, a, 0, 0, 0);
      a = __builtin_amdgcn_mfma_f32_16x16x32_bf16(a1.s, Bl1, a, 0, 0, 0);
      acc[n] = a;
    }

    float s0=0.f, s1=0.f, s2=0.f, s3=0.f;
#pragma unroll
    for (int n=0;n<4;++n){
      int o = n*16 + lcol;
      float wv = w2L[o];
      float bb = b1L[o];
      s0 += wv*gelu_f(acc[n][0] + bb);
      s1 += wv*gelu_f(acc[n][1] + bb);
      s2 += wv*gelu_f(acc[n][2] + bb);
      s3 += wv*gelu_f(acc[n][3] + bb);
    }
#pragma unroll
    for (int m=1;m<16;m<<=1){
      s0 += __shfl_xor(s0, m, 64);
      s1 += __shfl_xor(s1, m, 64);
      s2 += __shfl_xor(s2, m, 64);
      s3 += __shfl_xor(s3, m, 64);
    }
    if (lcol < 4){
      float v = (lcol==0) ? s0 : (lcol==1) ? s1 : (lcol==2) ? s2 : s3;
      out[((size_t)b*256 + x)*256 + mt*16 + quad*4 + lcol] = v + bias2;
    }
  }
}

extern "C" void kernel_launch(void* const* d_in, const int* in_sizes, int n_in,
                              void* d_out, int out_size, void* d_ws, size_t ws_size,
                              hipStream_t stream){
  const float* x    = (const float*)d_in[0];
  const float* liw  = (const float*)d_in[1];
  const float* lib  = (const float*)d_in[2];
  const float* w1   = (const float*)d_in[3];
  const float* w2   = (const float*)d_in[4];
  const float* cw   = (const float*)d_in[5];
  const float* cb   = (const float*)d_in[6];
  const float* gg   = (const float*)d_in[7];
  const float* gb   = (const float*)d_in[8];
  const float* dw1  = (const float*)d_in[9];
  const float* db1  = (const float*)d_in[10];
  const float* dw2  = (const float*)d_in[11];
  const float* db2  = (const float*)d_in[12];
  float* out = (float*)d_out;

  // ws: H 142.7MB bf16 | tmp 138MB f32 | zB 34.6MB bf16-hi/lo | Xf 4.2MB | oft 4.2MB | tables
  char* p = (char*)d_ws;
  ushort_t* H = (ushort_t*)p; p += (size_t)NBAT*NPIX*64*2;
  float* tmp  = (float*)p; p += (size_t)NBAT*264*32*64*4;
  ushort_t* zB = (ushort_t*)p; p += (size_t)NBAT*264*64*64*2;
  float* Xf   = (float*)p; p += (size_t)NIMG*512*2*4;
  float* oft  = (float*)p; p += (size_t)NIMG*512*2*4;
  float* tFT  = (float*)p; p += 8448*4;
  float* tCT  = (float*)p; p += 8448*4;
  float* tST  = (float*)p; p += 8448*4;
  ushort_t* TWh = (ushort_t*)p; p += 8704*2;
  ushort_t* TWl = (ushort_t*)p; p += 8704*2;
  ushort_t* cwB = (ushort_t*)p; p += 16384*2;
  float2* stats = (float2*)p; p += 64*8;

  k_tables<<<164, 256, 0, stream>>>(tFT, tCT, tST, TWh, TWl, cw, cwB);

  for (int k=0;k<NLAY;++k){
    if (k == 0)
      k_fwd_y0<<<1056, 256, 0, stream>>>(x, liw, lib, tFT, tmp);
    else
      k_fwd_y<<<1056, 256, 0, stream>>>(H, tFT, tmp);
    k_fwd_x<<<dim3(128,16), 256, 0, stream>>>(tmp, tCT, tST, Xf);
    k_mix<<<dim3(64,4), 512, 0, stream>>>(Xf, w1 + (size_t)k*2097152, w2 + (size_t)k*2097152, oft);
    k_stats_spec<<<64, 256, 0, stream>>>(oft, stats);
    k_inv_x<<<1024, 256, 0, stream>>>(oft, tCT, tST, zB, stats, gg + (size_t)k*64);
    k_fused2<<<dim3(264,16), 512, 0, stream>>>(H, zB, cwB + (size_t)k*4096, cb + (size_t)k*64,
                                               gg + (size_t)k*64, gb + (size_t)k*64, stats, TWh, TWl,
                                               x, liw, lib, (k<3)?1:0, (k==0)?1:0);
  }
  k_dec<<<dim3(256,16), 256, 0, stream>>>(H, dw1, db1, dw2, db2, out);
}

// Round 11
// 1340.073 us; speedup vs baseline: 1.1438x; 1.0238x over previous
//
#include <hip/hip_runtime.h>
#include <hip/hip_bf16.h>
#include <math.h>

#define PH   264
#define NPIX (PH*PH)          // 69696
#define NBAT 16
#define NIMG (NBAT*64)        // 1024
#define NLAY 4

typedef unsigned short ushort_t;
typedef unsigned int   uint_t;
typedef __attribute__((ext_vector_type(8))) short short8;   // 8 bf16 = 4 VGPR (MFMA A/B frag)
typedef __attribute__((ext_vector_type(4))) float float4v;  // MFMA C/D frag

__device__ __forceinline__ float blo(uint_t u){ union{uint_t u; float f;} v; v.u = u << 16;        return v.f; }
__device__ __forceinline__ float bhi(uint_t u){ union{uint_t u; float f;} v; v.u = u & 0xffff0000u; return v.f; }
__device__ __forceinline__ float b2f(ushort_t s){ union{uint_t u; float f;} v; v.u = ((uint_t)s) << 16; return v.f; }
__device__ __forceinline__ ushort_t f2b(float f){
  __hip_bfloat16 h = __float2bfloat16(f);
  union{__hip_bfloat16 h; ushort_t s;} v; v.h = h; return v.s;
}
// tanh-form gelu via sigmoid identity 0.5(1+tanh(z)) = sigma(2z):
//   gelu(v) ~= v / (1 + exp2(-2.3022082*(v + 0.044715 v^3)))
// 8 VALU ops vs 18 for the A&S erf form. |err vs exact erf-gelu| ~3e-4 abs — an order below
// bf16 storage quantization. R10: gelu was ~58us of k_fused2's 88us (71.4M gelu/dispatch).
__device__ __forceinline__ float gelu_f(float v){
  float x2 = v*v;
  float u  = v*fmaf(0.044715f, x2, 1.0f);
  float e  = __builtin_amdgcn_exp2f(-2.3022082f*u);
  return v*__builtin_amdgcn_rcpf(1.0f + e);
}

// DFT twiddle tables (fp32, exact integer-mod phase) + bf16 hi/lo inv-y twiddle TWg[272][32]
// + bf16 conv weights cwB[L][o][i] (one-time convert; same rounding as per-layer f2b before).
__global__ __launch_bounds__(256) void k_tables(float* __restrict__ tFT, float* __restrict__ tCT,
                                                float* __restrict__ tST,
                                                ushort_t* __restrict__ TWh, ushort_t* __restrict__ TWl,
                                                const float* __restrict__ cw, ushort_t* __restrict__ cwB){
  int idx = blockIdx.x*256 + threadIdx.x;
  const double W0 = 6.283185307179586 / 264.0;
  if (idx < 8448){                       // tFT[y*32+kk]: kk=2k -> cos, 2k+1 -> -sin (e^{-i 2pi k y/264})
    int y = idx >> 5, kk = idx & 31, k = kk >> 1;
    int ph = (k*y) % 264;
    float ang = (float)(W0 * ph), s, c;
    sincosf(ang, &s, &c);
    tFT[idx] = (kk & 1) ? -s : c;
  } else if (idx < 16896){               // tCT/tST[x*32+kxi]: cos/sin(2pi kxe x/264), kxe in [-16,15]
    int d = idx - 8448;
    int x = d >> 5, kxi = d & 31;
    int kxe = (kxi < 16) ? kxi : kxi - 32;
    int ph = ((kxe*x) % 264 + 264) % 264;
    float ang = (float)(W0 * ph), s, c;
    sincosf(ang, &s, &c);
    tCT[d] = c; tST[d] = s;
  } else if (idx < 16896 + 8704){        // TWg[y][kk]: inv-y row; rows >=264 zero (padding m-tile)
    int d = idx - 16896;
    int y = d >> 5, kk = d & 31;
    float v = 0.f;
    if (y < 264){
      if (kk == 0) v = 0.5f;
      else if (kk > 1){
        int j = kk >> 1;
        int ph = (j*y) % 264;
        float ang = (float)(W0 * ph), s, c;
        sincosf(ang, &s, &c);
        v = (kk & 1) ? -s : c;
      }
    }
    ushort_t hi = f2b(v);
    TWh[d] = hi;
    TWl[d] = f2b(v - b2f(hi));
  } else if (idx < 25600 + 16384){       // cwB: all 4 layers, bf16
    int d = idx - 25600;
    cwB[d] = f2b(cw[d]);
  }
}

// fwd DFT along y, LAYER 0: lift computed inline from xin (fp32) — no materialized H read.
// tmp[b][x][kk][c] = sum_{y<256} (lw[c]*xin[b,x,y]+lb[c]) * tFT[y][kk];  rows x>=256 are zero.
__global__ __launch_bounds__(256) void k_fwd_y0(const float* __restrict__ xin, const float* __restrict__ lw,
                                                const float* __restrict__ lb, const float* __restrict__ tFT,
                                                float* __restrict__ tmp){
  int t = threadIdx.x;
  int row = blockIdx.x*4 + (t>>6);        // 0..4223 = b*264+x
  int c = t & 63;
  int b = row / 264, x = row - b*264;
  float acc[32];
#pragma unroll
  for (int j=0;j<32;++j) acc[j]=0.f;
  if (x < 256){
    float lwc = lw[c], lbc = lb[c];
    const float* xp = xin + ((size_t)(b*256+x))*256;
    for (int y=0; y<256; ++y){
      float h = lwc*xp[y] + lbc;          // xp[y] wave-uniform broadcast
      const float* fr = tFT + y*32;
#pragma unroll
      for (int j=0;j<32;++j) acc[j] += h*fr[j];
    }
  }
  float* op = tmp + (((size_t)row)*32)*64 + c;
#pragma unroll
  for (int j=0;j<32;++j) op[(size_t)j*64] = acc[j];
}

// fwd DFT along y (layers 1..3): tmp[b][x][kk][c] = sum_y H[b][x*264+y][c] * tFT[y][kk]
__global__ __launch_bounds__(256) void k_fwd_y(const ushort_t* __restrict__ H, const float* __restrict__ tFT,
                                               float* __restrict__ tmp){
  int t = threadIdx.x;
  int row = blockIdx.x*4 + (t>>6);        // 0..4223 = b*264+x
  int c = t & 63;
  int b = row / 264, x = row - b*264;
  const ushort_t* hp = H + ((size_t)b*NPIX + (size_t)x*PH)*64 + c;
  float acc[32];
#pragma unroll
  for (int j=0;j<32;++j) acc[j]=0.f;
  for (int y=0; y<PH; ++y){
    float h = b2f(hp[(size_t)y*64]);
    const float* fr = tFT + y*32;         // wave-uniform
#pragma unroll
    for (int j=0;j<32;++j) acc[j] += h*fr[j];
  }
  float* op = tmp + (((size_t)row)*32)*64 + c;
#pragma unroll
  for (int j=0;j<32;++j) op[(size_t)j*64] = acc[j];
}

// fwd DFT along x: Xf[img=(b*64+c)][m] = sum_x tmp[b][x][ky-pair][c] * e^{-i..}
__global__ __launch_bounds__(256) void k_fwd_x(const float* __restrict__ tmp, const float* __restrict__ tCT,
                                               const float* __restrict__ tST, float* __restrict__ Xf){
  int t = threadIdx.x, b = blockIdx.y;
  int m = blockIdx.x*4 + (t>>6);          // 0..511
  int c = t & 63;
  int kxi = m >> 4, ky = m & 15;
  float xr=0.f, xi=0.f;
  const float* base = tmp + ((size_t)b*264*32 + 2*ky)*64 + c;
  for (int x=0; x<PH; ++x){
    float tr = base[(size_t)x*32*64];
    float ti = base[(size_t)x*32*64 + 64];
    float cc = tCT[x*32+kxi], ss = tST[x*32+kxi];   // wave-uniform
    xr += tr*cc + ti*ss;
    xi += ti*cc - tr*ss;
  }
  ((float2*)Xf)[(size_t)(b*64+c)*512 + m] = make_float2(xr, xi);
}

// per-mode 64x64 complex channel mix (unchanged)
__global__ __launch_bounds__(512) void k_mix(const float* __restrict__ Xf, const float* __restrict__ w1,
                                             const float* __restrict__ w2, float* __restrict__ oft){
  int m = threadIdx.x;
  int o = blockIdx.x;
  int b0 = blockIdx.y*4;
  const float2* X = (const float2*)Xf;
  const float2* W = (const float2*)((m < 256) ? w1 : w2);
  int mm = m & 255;
  float2 acc[4];
#pragma unroll
  for (int b=0;b<4;++b) acc[b] = make_float2(0.f,0.f);
  for (int i=0;i<64;++i){
    float2 w = W[(size_t)(i*64+o)*256 + mm];
#pragma unroll
    for (int b=0;b<4;++b){
      float2 x = X[((size_t)((b0+b)*64+i)*512) + m];
      acc[b].x += x.x*w.x - x.y*w.y;
      acc[b].y += x.x*w.y + x.y*w.x;
    }
  }
  float2* O = (float2*)oft;
#pragma unroll
  for (int b=0;b<4;++b) O[((size_t)((b0+b)*64+o)*512) + m] = acc[b];
}

// GroupNorm stats from oft via Parseval (unchanged)
__global__ __launch_bounds__(256) void k_stats_spec(const float* __restrict__ oft, float2* __restrict__ stats){
  __shared__ float sq[256], s1s[256];
  int bg = blockIdx.x, t = threadIdx.x;
  int b = bg >> 2, g = bg & 3;
  const float2* O = (const float2*)oft;
  float q = 0.f, s1 = 0.f;
  for (int c16=0; c16<16; ++c16){
    const float2* Op = O + (size_t)(b*64 + g*16 + c16)*512;
    for (int m=t; m<512; m+=256){
      if (m & 15){ float2 v = Op[m]; q += 2.f*(v.x*v.x + v.y*v.y); }
    }
  }
  {
    int c16 = t >> 4, j = t & 15;
    const float2* Op = O + (size_t)(b*64 + g*16 + c16)*512;
    if (j == 0){
      float2 a0 = Op[0];
      s1 = a0.x;
      q += a0.x*a0.x;
      float2 h16 = Op[16*16];
      q += 0.5f*(h16.x*h16.x + h16.y*h16.y);
    } else {
      float2 a = Op[j*16];
      float2 bb = Op[(32-j)*16];
      float rr = a.x + bb.x, ii = a.y - bb.y;
      q += 0.5f*(rr*rr + ii*ii);
    }
  }
  sq[t] = q; s1s[t] = s1; __syncthreads();
  for (int st_=128; st_>0; st_>>=1){
    if (t < st_){ sq[t] += sq[t+st_]; s1s[t] += s1s[t+st_]; }
    __syncthreads();
  }
  if (t == 0){
    const float invN = 1.0f/1115136.0f;
    float mu  = s1s[0]*invN;
    float ssq = sq[0]*(1.0f/69696.0f);
    float var = fmaxf(ssq*invN - mu*mu, 0.f);
    stats[bg] = make_float2(mu, 1.0f/sqrtf(var + 1e-5f));
  }
}

// inverse DFT along x, emitting MFMA-B-ready hi/lo bf16 planes premultiplied by
// alpha = rstd*gamma*(2/69696):  zB[((b*264+x)*64 + c)*64 + {0..31:hi, 32..63:lo}]
__global__ __launch_bounds__(256) void k_inv_x(const float* __restrict__ oft, const float* __restrict__ tCT,
                                               const float* __restrict__ tST, ushort_t* __restrict__ zB,
                                               const float2* __restrict__ stats, const float* __restrict__ gg){
  __shared__ float sof[1024];
  int t = threadIdx.x, img = blockIdx.x;
  int b = img >> 6, c = img & 63;
  const float* op = oft + (size_t)img*1024;
  for (int d=t; d<1024; d+=256) sof[d] = op[d];
  __syncthreads();
  float al = stats[b*4 + (c>>4)].y * gg[c] * (2.0f/69696.0f);
  for (int x=t; x<264; x+=256){
    float zr[16], zi[16];
#pragma unroll
    for (int k=0;k<16;++k){ zr[k]=0.f; zi[k]=0.f; }
    for (int kxi=0; kxi<32; ++kxi){
      float cc = tCT[x*32+kxi], ss = tST[x*32+kxi];
#pragma unroll
      for (int ky=0; ky<16; ++ky){
        float orr = sof[(kxi*16+ky)*2], oii = sof[(kxi*16+ky)*2 + 1];
        zr[ky] += orr*cc - oii*ss;
        zi[ky] += oii*cc + orr*ss;
      }
    }
    uint_t wh[16], wl[16];
#pragma unroll
    for (int k=0;k<16;++k){
      float a = zr[k]*al, bb2 = zi[k]*al;
      ushort_t ah = f2b(a),  bh = f2b(bb2);
      ushort_t alo = f2b(a - b2f(ah)), blo_ = f2b(bb2 - b2f(bh));
      wh[k] = (uint_t)ah | ((uint_t)bh << 16);
      wl[k] = (uint_t)alo | ((uint_t)blo_ << 16);
    }
    uint4* dst = (uint4*)(zB + ((size_t)((size_t)(b*264 + x)*64 + c))*64);
#pragma unroll
    for (int q=0;q<4;++q) dst[q]   = ((uint4*)wh)[q];
#pragma unroll
    for (int q=0;q<4;++q) dst[4+q] = ((uint4*)wl)[q];
  }
}

// Row-tile MFMA fused layer: H(new) = gelu( TW·(z·alpha) + H·Wconv + beta ), in place on H.
// grid (264 x-rows, 16 b); 512 thr = 8 waves; wave w owns m-tiles {w, w+8, (16 if w==0)}.
// B operands (zB hi/lo, cwB) PRECOMPUTED in global, staged to LDS (uint4 copy); MFMA LDS-fed.
// lay0: A(conv) computed INLINE from xin/lw/lb (lift fused).
// LDS: obuf ALIASES zBs/cws (dead after MFMA loop, barrier-protected) -> 19KB total, and
// __launch_bounds__(512,4) pins <=128 unified regs -> 2 blocks/CU (R9: 126us->88us).
// R3 lesson: watch for spill signature (VGPR drop + FETCH/WRITE balloon) -> revert bound.
__global__ __launch_bounds__(512, 4) void k_fused2(ushort_t* __restrict__ H,
                                                const ushort_t* __restrict__ zB,
                                                const ushort_t* __restrict__ cwB,
                                                const float* __restrict__ cb,
                                                const float* __restrict__ gg, const float* __restrict__ gb,
                                                const float2* __restrict__ stats,
                                                const ushort_t* __restrict__ TWh, const ushort_t* __restrict__ TWl,
                                                const float* __restrict__ xin, const float* __restrict__ lw,
                                                const float* __restrict__ lb,
                                                int do_gelu, int lay0){
  __shared__ short smem[9216];               // phase1: zBs[0..4607], cws[4608..9215] (stride 72)
                                             // phase2 (after barrier): obuf[w] = smem + w*1152
  __shared__ float lwL[64], lbL[64];
  short* zBs = smem;
  short* cws = smem + 4608;
  int t = threadIdx.x, b = blockIdx.y, x = blockIdx.x;
  int w = t >> 6, lane = t & 63;
  int quad = lane >> 4, lcol = lane & 15;

  // stage: one uint4 per thread per buffer (8KB each), stride-64 -> stride-72 repack
  {
    int row = t >> 3, q = t & 7;
    const uint4* zsrc = (const uint4*)(zB + ((size_t)(b*264 + x))*64*64);
    *(uint4*)&zBs[row*72 + q*8] = zsrc[t];
    *(uint4*)&cws[row*72 + q*8] = ((const uint4*)cwB)[t];
  }
  if (t < 64){ lwL[t] = lw[t]; lbL[t] = lb[t]; }
  __syncthreads();

  float4v acc[3][4];
#pragma unroll
  for (int si=0;si<3;++si)
#pragma unroll
    for (int n=0;n<4;++n) acc[si][n] = (float4v){0.f,0.f,0.f,0.f};

#pragma unroll
  for (int si=0;si<3;++si){
    int mt = w + 8*si;
    if (mt > 16) break;                       // wave-uniform
    int pxl = mt*16 + lcol;                   // local px (row y) 0..271
    union{uint4 u; short8 s;} a0, a1;
    a0.u = make_uint4(0,0,0,0); a1.u = make_uint4(0,0,0,0);
    if (lay0){
      bool in = (x < 256) && (pxl < 256);
      float xv = in ? xin[((size_t)(b*256+x))*256 + pxl] : 0.f;
      uint_t wa[8];
#pragma unroll
      for (int j=0;j<4;++j){
        int ch = quad*8 + 2*j;
        float v0 = in ? (lwL[ch  ]*xv + lbL[ch  ]) : 0.f;
        float v1 = in ? (lwL[ch+1]*xv + lbL[ch+1]) : 0.f;
        wa[j] = (uint_t)f2b(v0) | ((uint_t)f2b(v1) << 16);
        float v2 = in ? (lwL[ch+32]*xv + lbL[ch+32]) : 0.f;
        float v3 = in ? (lwL[ch+33]*xv + lbL[ch+33]) : 0.f;
        wa[4+j] = (uint_t)f2b(v2) | ((uint_t)f2b(v3) << 16);
      }
      a0.u = make_uint4(wa[0], wa[1], wa[2], wa[3]);
      a1.u = make_uint4(wa[4], wa[5], wa[6], wa[7]);
    } else if (pxl < PH){
      const ushort_t* hp = H + ((size_t)b*NPIX + (size_t)x*PH + pxl)*64 + quad*8;
      a0.u = *(const uint4*)hp;
      a1.u = *(const uint4*)(hp + 32);
    }
    short8 Th = *(const short8*)(TWh + pxl*32 + quad*8);
    short8 Tl = *(const short8*)(TWl + pxl*32 + quad*8);
#pragma unroll
    for (int n=0;n<4;++n){
      float4v a = acc[si][n];
      short8 Bc0 = *(const short8*)&cws[(n*16+lcol)*72 + quad*8];
      short8 Bc1 = *(const short8*)&cws[(n*16+lcol)*72 + 32 + quad*8];
      a = __builtin_amdgcn_mfma_f32_16x16x32_bf16(a0.s, Bc0, a, 0, 0, 0);
      a = __builtin_amdgcn_mfma_f32_16x16x32_bf16(a1.s, Bc1, a, 0, 0, 0);
      short8 Bzh = *(const short8*)&zBs[(n*16+lcol)*72 + quad*8];
      short8 Bzl = *(const short8*)&zBs[(n*16+lcol)*72 + 32 + quad*8];
      a = __builtin_amdgcn_mfma_f32_16x16x32_bf16(Th, Bzh, a, 0, 0, 0);
      a = __builtin_amdgcn_mfma_f32_16x16x32_bf16(Th, Bzl, a, 0, 0, 0);
      a = __builtin_amdgcn_mfma_f32_16x16x32_bf16(Tl, Bzh, a, 0, 0, 0);
      acc[si][n] = a;
    }
  }

  __syncthreads();   // zBs/cws dead for ALL waves -> obuf may alias them

  // epilogue: + (gb - mu*rstd*g + cb), gelu, bounce through per-wave LDS, full-line stores.
  float beta[4];
#pragma unroll
  for (int n=0;n<4;++n){
    int o = n*16 + lcol;
    float2 st = stats[b*4 + n];
    beta[n] = gb[o] - st.x*st.y*gg[o] + cb[o];
  }
  short* ob = smem + w*1152;                 // 16 px * stride 72
#pragma unroll
  for (int si=0;si<3;++si){
    int mt = w + 8*si;
    if (mt > 16) break;
#pragma unroll
    for (int reg=0; reg<4; ++reg){
      int prow = quad*4 + reg;
#pragma unroll
      for (int n=0;n<4;++n){
        float v = acc[si][n][reg] + beta[n];
        if (do_gelu) v = gelu_f(v);
        ob[prow*72 + n*16 + lcol] = (short)f2b(v);
      }
    }
    asm volatile("s_waitcnt lgkmcnt(0)" ::: "memory");   // wave-local: writes visible to own lanes
#pragma unroll
    for (int p=0;p<2;++p){
      int prow2 = p*8 + (lane>>3);
      int c0 = (lane&7)*8;
      int pxl2 = mt*16 + prow2;
      if (pxl2 < PH){
        uint4 u = *(const uint4*)&ob[prow2*72 + c0];
        *(uint4*)(H + ((size_t)b*NPIX + (size_t)x*PH + pxl2)*64 + c0) = u;
      }
    }
    asm volatile("" ::: "memory");   // keep next si's obuf writes below these reads
  }
}

// decoder: crop -> dec1 -> gelu -> dec2, MFMA version.
__global__ __launch_bounds__(256) void k_dec(const ushort_t* __restrict__ H, const float* __restrict__ w1,
                                             const float* __restrict__ b1, const float* __restrict__ w2,
                                             const float* __restrict__ b2, float* __restrict__ out){
  __shared__ short w1h[64*72], w1l[64*72];   // [o][c] hi/lo, stride 72 (16B aligned rows)
  __shared__ float w2L[64], b1L[64];
  int t = threadIdx.x, x = blockIdx.x, b = blockIdx.y;
  for (int d=t; d<4096; d+=256){
    int o = d>>6, c = d&63;
    float v = w1[o*64+c];
    ushort_t hi = f2b(v);
    w1h[o*72+c] = (short)hi;
    w1l[o*72+c] = (short)f2b(v - b2f(hi));
  }
  if (t < 64){ w2L[t] = w2[t]; b1L[t] = b1[t]; }
  __syncthreads();

  int w = t >> 6, lane = t & 63;
  int quad = lane >> 4, lcol = lane & 15;
  float bias2 = b2[0];

#pragma unroll
  for (int i=0;i<4;++i){
    int mt = w*4 + i;                        // 0..15 -> y = mt*16+lcol, all < 256 (crop)
    int py = mt*16 + lcol;
    const ushort_t* hp = H + ((size_t)b*NPIX + (size_t)x*PH + py)*64 + quad*8;
    union{uint4 u; short8 s;} a0, a1;
    a0.u = *(const uint4*)hp;
    a1.u = *(const uint4*)(hp + 32);

    float4v acc[4];
#pragma unroll
    for (int n=0;n<4;++n) acc[n] = (float4v){0.f,0.f,0.f,0.f};
#pragma unroll
    for (int n=0;n<4;++n){
      float4v a = acc[n];
      short8 Bh0 = *(const short8*)&w1h[(n*16+lcol)*72 + quad*8];
      short8 Bh1 = *(const short8*)&w1h[(n*16+lcol)*72 + 32 + quad*8];
      short8 Bl0 = *(const short8*)&w1l[(n*16+lcol)*72 + quad*8];
      short8 Bl1 = *(const short8*)&w1l[(n*16+lcol)*72 + 32 + quad*8];
      a = __builtin_amdgcn_mfma_f32_16x16x32_bf16(a0.s, Bh0, a, 0, 0, 0);
      a = __builtin_amdgcn_mfma_f32_16x16x32_bf16(a1.s, Bh1, a, 0, 0, 0);
      a = __builtin_amdgcn_mfma_f32_16x16x32_bf16(a0.s, Bl0, a, 0, 0, 0);
      a = __builtin_amdgcn_mfma_f32_16x16x32_bf16(a1.s, Bl1, a, 0, 0, 0);
      acc[n] = a;
    }

    float s0=0.f, s1=0.f, s2=0.f, s3=0.f;
#pragma unroll
    for (int n=0;n<4;++n){
      int o = n*16 + lcol;
      float wv = w2L[o];
      float bb = b1L[o];
      s0 += wv*gelu_f(acc[n][0] + bb);
      s1 += wv*gelu_f(acc[n][1] + bb);
      s2 += wv*gelu_f(acc[n][2] + bb);
      s3 += wv*gelu_f(acc[n][3] + bb);
    }
#pragma unroll
    for (int m=1;m<16;m<<=1){
      s0 += __shfl_xor(s0, m, 64);
      s1 += __shfl_xor(s1, m, 64);
      s2 += __shfl_xor(s2, m, 64);
      s3 += __shfl_xor(s3, m, 64);
    }
    if (lcol < 4){
      float v = (lcol==0) ? s0 : (lcol==1) ? s1 : (lcol==2) ? s2 : s3;
      out[((size_t)b*256 + x)*256 + mt*16 + quad*4 + lcol] = v + bias2;
    }
  }
}

extern "C" void kernel_launch(void* const* d_in, const int* in_sizes, int n_in,
                              void* d_out, int out_size, void* d_ws, size_t ws_size,
                              hipStream_t stream){
  const float* x    = (const float*)d_in[0];
  const float* liw  = (const float*)d_in[1];
  const float* lib  = (const float*)d_in[2];
  const float* w1   = (const float*)d_in[3];
  const float* w2   = (const float*)d_in[4];
  const float* cw   = (const float*)d_in[5];
  const float* cb   = (const float*)d_in[6];
  const float* gg   = (const float*)d_in[7];
  const float* gb   = (const float*)d_in[8];
  const float* dw1  = (const float*)d_in[9];
  const float* db1  = (const float*)d_in[10];
  const float* dw2  = (const float*)d_in[11];
  const float* db2  = (const float*)d_in[12];
  float* out = (float*)d_out;

  // ws: H 142.7MB bf16 | tmp 138MB f32 | zB 34.6MB bf16-hi/lo | Xf 4.2MB | oft 4.2MB | tables
  char* p = (char*)d_ws;
  ushort_t* H = (ushort_t*)p; p += (size_t)NBAT*NPIX*64*2;
  float* tmp  = (float*)p; p += (size_t)NBAT*264*32*64*4;
  ushort_t* zB = (ushort_t*)p; p += (size_t)NBAT*264*64*64*2;
  float* Xf   = (float*)p; p += (size_t)NIMG*512*2*4;
  float* oft  = (float*)p; p += (size_t)NIMG*512*2*4;
  float* tFT  = (float*)p; p += 8448*4;
  float* tCT  = (float*)p; p += 8448*4;
  float* tST  = (float*)p; p += 8448*4;
  ushort_t* TWh = (ushort_t*)p; p += 8704*2;
  ushort_t* TWl = (ushort_t*)p; p += 8704*2;
  ushort_t* cwB = (ushort_t*)p; p += 16384*2;
  float2* stats = (float2*)p; p += 64*8;

  k_tables<<<164, 256, 0, stream>>>(tFT, tCT, tST, TWh, TWl, cw, cwB);

  for (int k=0;k<NLAY;++k){
    if (k == 0)
      k_fwd_y0<<<1056, 256, 0, stream>>>(x, liw, lib, tFT, tmp);
    else
      k_fwd_y<<<1056, 256, 0, stream>>>(H, tFT, tmp);
    k_fwd_x<<<dim3(128,16), 256, 0, stream>>>(tmp, tCT, tST, Xf);
    k_mix<<<dim3(64,4), 512, 0, stream>>>(Xf, w1 + (size_t)k*2097152, w2 + (size_t)k*2097152, oft);
    k_stats_spec<<<64, 256, 0, stream>>>(oft, stats);
    k_inv_x<<<1024, 256, 0, stream>>>(oft, tCT, tST, zB, stats, gg + (size_t)k*64);
    k_fused2<<<dim3(264,16), 512, 0, stream>>>(H, zB, cwB + (size_t)k*4096, cb + (size_t)k*64,
                                               gg + (size_t)k*64, gb + (size_t)k*64, stats, TWh, TWl,
                                               x, liw, lib, (k<3)?1:0, (k==0)?1:0);
  }
  k_dec<<<dim3(256,16), 256, 0, stream>>>(H, dw1, db1, dw2, db2, out);
}

// Round 12
// 1329.353 us; speedup vs baseline: 1.1530x; 1.0081x over previous
//
#include <hip/hip_runtime.h>
#include <hip/hip_bf16.h>
#include <math.h>

#define PH   264
#define NPIX (PH*PH)          // 69696
#define NBAT 16
#define NIMG (NBAT*64)        // 1024
#define NLAY 4

typedef unsigned short ushort_t;
typedef unsigned int   uint_t;
typedef _Float16       half_t;
typedef __attribute__((ext_vector_type(8))) short short8;   // 8 bf16 = 4 VGPR (MFMA A/B frag)
typedef __attribute__((ext_vector_type(4))) float float4v;  // MFMA C/D frag

__device__ __forceinline__ float blo(uint_t u){ union{uint_t u; float f;} v; v.u = u << 16;        return v.f; }
__device__ __forceinline__ float bhi(uint_t u){ union{uint_t u; float f;} v; v.u = u & 0xffff0000u; return v.f; }
__device__ __forceinline__ float b2f(ushort_t s){ union{uint_t u; float f;} v; v.u = ((uint_t)s) << 16; return v.f; }
__device__ __forceinline__ ushort_t f2b(float f){
  __hip_bfloat16 h = __float2bfloat16(f);
  union{__hip_bfloat16 h; ushort_t s;} v; v.h = h; return v.s;
}
// tanh-form gelu via sigmoid identity 0.5(1+tanh(z)) = sigma(2z):
//   gelu(v) ~= v / (1 + exp2(-2.3022082*(v + 0.044715 v^3)))
// 8 VALU ops; |err vs exact erf-gelu| ~3e-4 abs — an order below bf16 storage quantization.
__device__ __forceinline__ float gelu_f(float v){
  float x2 = v*v;
  float u  = v*fmaf(0.044715f, x2, 1.0f);
  float e  = __builtin_amdgcn_exp2f(-2.3022082f*u);
  return v*__builtin_amdgcn_rcpf(1.0f + e);
}

// DFT twiddle tables (fp32, exact integer-mod phase) + bf16 hi/lo inv-y twiddle TWg[272][32]
// + bf16 conv weights cwB[L][o][i] (one-time convert; same rounding as per-layer f2b before).
__global__ __launch_bounds__(256) void k_tables(float* __restrict__ tFT, float* __restrict__ tCT,
                                                float* __restrict__ tST,
                                                ushort_t* __restrict__ TWh, ushort_t* __restrict__ TWl,
                                                const float* __restrict__ cw, ushort_t* __restrict__ cwB){
  int idx = blockIdx.x*256 + threadIdx.x;
  const double W0 = 6.283185307179586 / 264.0;
  if (idx < 8448){                       // tFT[y*32+kk]: kk=2k -> cos, 2k+1 -> -sin (e^{-i 2pi k y/264})
    int y = idx >> 5, kk = idx & 31, k = kk >> 1;
    int ph = (k*y) % 264;
    float ang = (float)(W0 * ph), s, c;
    sincosf(ang, &s, &c);
    tFT[idx] = (kk & 1) ? -s : c;
  } else if (idx < 16896){               // tCT/tST[x*32+kxi]: cos/sin(2pi kxe x/264), kxe in [-16,15]
    int d = idx - 8448;
    int x = d >> 5, kxi = d & 31;
    int kxe = (kxi < 16) ? kxi : kxi - 32;
    int ph = ((kxe*x) % 264 + 264) % 264;
    float ang = (float)(W0 * ph), s, c;
    sincosf(ang, &s, &c);
    tCT[d] = c; tST[d] = s;
  } else if (idx < 16896 + 8704){        // TWg[y][kk]: inv-y row; rows >=264 zero (padding m-tile)
    int d = idx - 16896;
    int y = d >> 5, kk = d & 31;
    float v = 0.f;
    if (y < 264){
      if (kk == 0) v = 0.5f;
      else if (kk > 1){
        int j = kk >> 1;
        int ph = (j*y) % 264;
        float ang = (float)(W0 * ph), s, c;
        sincosf(ang, &s, &c);
        v = (kk & 1) ? -s : c;
      }
    }
    ushort_t hi = f2b(v);
    TWh[d] = hi;
    TWl[d] = f2b(v - b2f(hi));
  } else if (idx < 25600 + 16384){       // cwB: all 4 layers, bf16
    int d = idx - 25600;
    cwB[d] = f2b(cw[d]);
  }
}

// fwd DFT along y, LAYER 0: lift computed inline from xin (fp32) — no materialized H read.
// tmp (fp16, 69MB: keeps tmp+H inside the 256MB L3 so H stays resident for k_fused2/k_fwd_y;
// fp16 rel err 5e-4, an order below the path's bf16 noise; |tmp| << fp16 range).
__global__ __launch_bounds__(256) void k_fwd_y0(const float* __restrict__ xin, const float* __restrict__ lw,
                                                const float* __restrict__ lb, const float* __restrict__ tFT,
                                                half_t* __restrict__ tmp){
  int t = threadIdx.x;
  int row = blockIdx.x*4 + (t>>6);        // 0..4223 = b*264+x
  int c = t & 63;
  int b = row / 264, x = row - b*264;
  float acc[32];
#pragma unroll
  for (int j=0;j<32;++j) acc[j]=0.f;
  if (x < 256){
    float lwc = lw[c], lbc = lb[c];
    const float* xp = xin + ((size_t)(b*256+x))*256;
    for (int y=0; y<256; ++y){
      float h = lwc*xp[y] + lbc;          // xp[y] wave-uniform broadcast
      const float* fr = tFT + y*32;
#pragma unroll
      for (int j=0;j<32;++j) acc[j] += h*fr[j];
    }
  }
  half_t* op = tmp + (((size_t)row)*32)*64 + c;
#pragma unroll
  for (int j=0;j<32;++j) op[(size_t)j*64] = (half_t)acc[j];
}

// fwd DFT along y (layers 1..3): tmp[b][x][kk][c] = sum_y H[b][x*264+y][c] * tFT[y][kk]
__global__ __launch_bounds__(256) void k_fwd_y(const ushort_t* __restrict__ H, const float* __restrict__ tFT,
                                               half_t* __restrict__ tmp){
  int t = threadIdx.x;
  int row = blockIdx.x*4 + (t>>6);        // 0..4223 = b*264+x
  int c = t & 63;
  int b = row / 264, x = row - b*264;
  const ushort_t* hp = H + ((size_t)b*NPIX + (size_t)x*PH)*64 + c;
  float acc[32];
#pragma unroll
  for (int j=0;j<32;++j) acc[j]=0.f;
  for (int y=0; y<PH; ++y){
    float h = b2f(hp[(size_t)y*64]);
    const float* fr = tFT + y*32;         // wave-uniform
#pragma unroll
    for (int j=0;j<32;++j) acc[j] += h*fr[j];
  }
  half_t* op = tmp + (((size_t)row)*32)*64 + c;
#pragma unroll
  for (int j=0;j<32;++j) op[(size_t)j*64] = (half_t)acc[j];
}

// fwd DFT along x: Xf[img=(b*64+c)][m] = sum_x tmp[b][x][ky-pair][c] * e^{-i..}
__global__ __launch_bounds__(256) void k_fwd_x(const half_t* __restrict__ tmp, const float* __restrict__ tCT,
                                               const float* __restrict__ tST, float* __restrict__ Xf){
  int t = threadIdx.x, b = blockIdx.y;
  int m = blockIdx.x*4 + (t>>6);          // 0..511
  int c = t & 63;
  int kxi = m >> 4, ky = m & 15;
  float xr=0.f, xi=0.f;
  const half_t* base = tmp + ((size_t)b*264*32 + 2*ky)*64 + c;
  for (int x=0; x<PH; ++x){
    float tr = (float)base[(size_t)x*32*64];
    float ti = (float)base[(size_t)x*32*64 + 64];
    float cc = tCT[x*32+kxi], ss = tST[x*32+kxi];   // wave-uniform
    xr += tr*cc + ti*ss;
    xi += ti*cc - tr*ss;
  }
  ((float2*)Xf)[(size_t)(b*64+c)*512 + m] = make_float2(xr, xi);
}

// per-mode 64x64 complex channel mix (unchanged)
__global__ __launch_bounds__(512) void k_mix(const float* __restrict__ Xf, const float* __restrict__ w1,
                                             const float* __restrict__ w2, float* __restrict__ oft){
  int m = threadIdx.x;
  int o = blockIdx.x;
  int b0 = blockIdx.y*4;
  const float2* X = (const float2*)Xf;
  const float2* W = (const float2*)((m < 256) ? w1 : w2);
  int mm = m & 255;
  float2 acc[4];
#pragma unroll
  for (int b=0;b<4;++b) acc[b] = make_float2(0.f,0.f);
  for (int i=0;i<64;++i){
    float2 w = W[(size_t)(i*64+o)*256 + mm];
#pragma unroll
    for (int b=0;b<4;++b){
      float2 x = X[((size_t)((b0+b)*64+i)*512) + m];
      acc[b].x += x.x*w.x - x.y*w.y;
      acc[b].y += x.x*w.y + x.y*w.x;
    }
  }
  float2* O = (float2*)oft;
#pragma unroll
  for (int b=0;b<4;++b) O[((size_t)((b0+b)*64+o)*512) + m] = acc[b];
}

// GroupNorm stats from oft via Parseval (unchanged)
__global__ __launch_bounds__(256) void k_stats_spec(const float* __restrict__ oft, float2* __restrict__ stats){
  __shared__ float sq[256], s1s[256];
  int bg = blockIdx.x, t = threadIdx.x;
  int b = bg >> 2, g = bg & 3;
  const float2* O = (const float2*)oft;
  float q = 0.f, s1 = 0.f;
  for (int c16=0; c16<16; ++c16){
    const float2* Op = O + (size_t)(b*64 + g*16 + c16)*512;
    for (int m=t; m<512; m+=256){
      if (m & 15){ float2 v = Op[m]; q += 2.f*(v.x*v.x + v.y*v.y); }
    }
  }
  {
    int c16 = t >> 4, j = t & 15;
    const float2* Op = O + (size_t)(b*64 + g*16 + c16)*512;
    if (j == 0){
      float2 a0 = Op[0];
      s1 = a0.x;
      q += a0.x*a0.x;
      float2 h16 = Op[16*16];
      q += 0.5f*(h16.x*h16.x + h16.y*h16.y);
    } else {
      float2 a = Op[j*16];
      float2 bb = Op[(32-j)*16];
      float rr = a.x + bb.x, ii = a.y - bb.y;
      q += 0.5f*(rr*rr + ii*ii);
    }
  }
  sq[t] = q; s1s[t] = s1; __syncthreads();
  for (int st_=128; st_>0; st_>>=1){
    if (t < st_){ sq[t] += sq[t+st_]; s1s[t] += s1s[t+st_]; }
    __syncthreads();
  }
  if (t == 0){
    const float invN = 1.0f/1115136.0f;
    float mu  = s1s[0]*invN;
    float ssq = sq[0]*(1.0f/69696.0f);
    float var = fmaxf(ssq*invN - mu*mu, 0.f);
    stats[bg] = make_float2(mu, 1.0f/sqrtf(var + 1e-5f));
  }
}

// inverse DFT along x, emitting MFMA-B-ready hi/lo bf16 planes premultiplied by
// alpha = rstd*gamma*(2/69696):  zB[((b*264+x)*64 + c)*64 + {0..31:hi, 32..63:lo}]
__global__ __launch_bounds__(256) void k_inv_x(const float* __restrict__ oft, const float* __restrict__ tCT,
                                               const float* __restrict__ tST, ushort_t* __restrict__ zB,
                                               const float2* __restrict__ stats, const float* __restrict__ gg){
  __shared__ float sof[1024];
  int t = threadIdx.x, img = blockIdx.x;
  int b = img >> 6, c = img & 63;
  const float* op = oft + (size_t)img*1024;
  for (int d=t; d<1024; d+=256) sof[d] = op[d];
  __syncthreads();
  float al = stats[b*4 + (c>>4)].y * gg[c] * (2.0f/69696.0f);
  for (int x=t; x<264; x+=256){
    float zr[16], zi[16];
#pragma unroll
    for (int k=0;k<16;++k){ zr[k]=0.f; zi[k]=0.f; }
    for (int kxi=0; kxi<32; ++kxi){
      float cc = tCT[x*32+kxi], ss = tST[x*32+kxi];
#pragma unroll
      for (int ky=0; ky<16; ++ky){
        float orr = sof[(kxi*16+ky)*2], oii = sof[(kxi*16+ky)*2 + 1];
        zr[ky] += orr*cc - oii*ss;
        zi[ky] += oii*cc + orr*ss;
      }
    }
    uint_t wh[16], wl[16];
#pragma unroll
    for (int k=0;k<16;++k){
      float a = zr[k]*al, bb2 = zi[k]*al;
      ushort_t ah = f2b(a),  bh = f2b(bb2);
      ushort_t alo = f2b(a - b2f(ah)), blo_ = f2b(bb2 - b2f(bh));
      wh[k] = (uint_t)ah | ((uint_t)bh << 16);
      wl[k] = (uint_t)alo | ((uint_t)blo_ << 16);
    }
    uint4* dst = (uint4*)(zB + ((size_t)((size_t)(b*264 + x)*64 + c))*64);
#pragma unroll
    for (int q=0;q<4;++q) dst[q]   = ((uint4*)wh)[q];
#pragma unroll
    for (int q=0;q<4;++q) dst[4+q] = ((uint4*)wl)[q];
  }
}

// Row-tile MFMA fused layer: H(new) = gelu( TW·(z·alpha) + H·Wconv + beta ), in place on H.
// grid (264 x-rows, 16 b); 512 thr = 8 waves; wave w owns m-tiles {w, w+8, (16 if w==0)}.
// B operands (zB hi/lo, cwB) PRECOMPUTED in global, staged to LDS (uint4 copy); MFMA LDS-fed.
// lay0: A(conv) computed INLINE from xin/lw/lb (lift fused).
// LDS: obuf ALIASES zBs/cws (dead after MFMA loop, barrier-protected) -> 19KB total, and
// __launch_bounds__(512,4) pins <=128 unified regs -> 2 blocks/CU (R9: 126us->88us).
__global__ __launch_bounds__(512, 4) void k_fused2(ushort_t* __restrict__ H,
                                                const ushort_t* __restrict__ zB,
                                                const ushort_t* __restrict__ cwB,
                                                const float* __restrict__ cb,
                                                const float* __restrict__ gg, const float* __restrict__ gb,
                                                const float2* __restrict__ stats,
                                                const ushort_t* __restrict__ TWh, const ushort_t* __restrict__ TWl,
                                                const float* __restrict__ xin, const float* __restrict__ lw,
                                                const float* __restrict__ lb,
                                                int do_gelu, int lay0){
  __shared__ short smem[9216];               // phase1: zBs[0..4607], cws[4608..9215] (stride 72)
                                             // phase2 (after barrier): obuf[w] = smem + w*1152
  __shared__ float lwL[64], lbL[64];
  short* zBs = smem;
  short* cws = smem + 4608;
  int t = threadIdx.x, b = blockIdx.y, x = blockIdx.x;
  int w = t >> 6, lane = t & 63;
  int quad = lane >> 4, lcol = lane & 15;

  // stage: one uint4 per thread per buffer (8KB each), stride-64 -> stride-72 repack
  {
    int row = t >> 3, q = t & 7;
    const uint4* zsrc = (const uint4*)(zB + ((size_t)(b*264 + x))*64*64);
    *(uint4*)&zBs[row*72 + q*8] = zsrc[t];
    *(uint4*)&cws[row*72 + q*8] = ((const uint4*)cwB)[t];
  }
  if (t < 64){ lwL[t] = lw[t]; lbL[t] = lb[t]; }
  __syncthreads();

  float4v acc[3][4];
#pragma unroll
  for (int si=0;si<3;++si)
#pragma unroll
    for (int n=0;n<4;++n) acc[si][n] = (float4v){0.f,0.f,0.f,0.f};

#pragma unroll
  for (int si=0;si<3;++si){
    int mt = w + 8*si;
    if (mt > 16) break;                       // wave-uniform
    int pxl = mt*16 + lcol;                   // local px (row y) 0..271
    union{uint4 u; short8 s;} a0, a1;
    a0.u = make_uint4(0,0,0,0); a1.u = make_uint4(0,0,0,0);
    if (lay0){
      bool in = (x < 256) && (pxl < 256);
      float xv = in ? xin[((size_t)(b*256+x))*256 + pxl] : 0.f;
      uint_t wa[8];
#pragma unroll
      for (int j=0;j<4;++j){
        int ch = quad*8 + 2*j;
        float v0 = in ? (lwL[ch  ]*xv + lbL[ch  ]) : 0.f;
        float v1 = in ? (lwL[ch+1]*xv + lbL[ch+1]) : 0.f;
        wa[j] = (uint_t)f2b(v0) | ((uint_t)f2b(v1) << 16);
        float v2 = in ? (lwL[ch+32]*xv + lbL[ch+32]) : 0.f;
        float v3 = in ? (lwL[ch+33]*xv + lbL[ch+33]) : 0.f;
        wa[4+j] = (uint_t)f2b(v2) | ((uint_t)f2b(v3) << 16);
      }
      a0.u = make_uint4(wa[0], wa[1], wa[2], wa[3]);
      a1.u = make_uint4(wa[4], wa[5], wa[6], wa[7]);
    } else if (pxl < PH){
      const ushort_t* hp = H + ((size_t)b*NPIX + (size_t)x*PH + pxl)*64 + quad*8;
      a0.u = *(const uint4*)hp;
      a1.u = *(const uint4*)(hp + 32);
    }
    short8 Th = *(const short8*)(TWh + pxl*32 + quad*8);
    short8 Tl = *(const short8*)(TWl + pxl*32 + quad*8);
#pragma unroll
    for (int n=0;n<4;++n){
      float4v a = acc[si][n];
      short8 Bc0 = *(const short8*)&cws[(n*16+lcol)*72 + quad*8];
      short8 Bc1 = *(const short8*)&cws[(n*16+lcol)*72 + 32 + quad*8];
      a = __builtin_amdgcn_mfma_f32_16x16x32_bf16(a0.s, Bc0, a, 0, 0, 0);
      a = __builtin_amdgcn_mfma_f32_16x16x32_bf16(a1.s, Bc1, a, 0, 0, 0);
      short8 Bzh = *(const short8*)&zBs[(n*16+lcol)*72 + quad*8];
      short8 Bzl = *(const short8*)&zBs[(n*16+lcol)*72 + 32 + quad*8];
      a = __builtin_amdgcn_mfma_f32_16x16x32_bf16(Th, Bzh, a, 0, 0, 0);
      a = __builtin_amdgcn_mfma_f32_16x16x32_bf16(Th, Bzl, a, 0, 0, 0);
      a = __builtin_amdgcn_mfma_f32_16x16x32_bf16(Tl, Bzh, a, 0, 0, 0);
      acc[si][n] = a;
    }
  }

  __syncthreads();   // zBs/cws dead for ALL waves -> obuf may alias them

  // epilogue: + (gb - mu*rstd*g + cb), gelu, bounce through per-wave LDS, full-line stores.
  float beta[4];
#pragma unroll
  for (int n=0;n<4;++n){
    int o = n*16 + lcol;
    float2 st = stats[b*4 + n];
    beta[n] = gb[o] - st.x*st.y*gg[o] + cb[o];
  }
  short* ob = smem + w*1152;                 // 16 px * stride 72
#pragma unroll
  for (int si=0;si<3;++si){
    int mt = w + 8*si;
    if (mt > 16) break;
#pragma unroll
    for (int reg=0; reg<4; ++reg){
      int prow = quad*4 + reg;
#pragma unroll
      for (int n=0;n<4;++n){
        float v = acc[si][n][reg] + beta[n];
        if (do_gelu) v = gelu_f(v);
        ob[prow*72 + n*16 + lcol] = (short)f2b(v);
      }
    }
    asm volatile("s_waitcnt lgkmcnt(0)" ::: "memory");   // wave-local: writes visible to own lanes
#pragma unroll
    for (int p=0;p<2;++p){
      int prow2 = p*8 + (lane>>3);
      int c0 = (lane&7)*8;
      int pxl2 = mt*16 + prow2;
      if (pxl2 < PH){
        uint4 u = *(const uint4*)&ob[prow2*72 + c0];
        *(uint4*)(H + ((size_t)b*NPIX + (size_t)x*PH + pxl2)*64 + c0) = u;
      }
    }
    asm volatile("" ::: "memory");   // keep next si's obuf writes below these reads
  }
}

// decoder: crop -> dec1 -> gelu -> dec2, MFMA version.
__global__ __launch_bounds__(256) void k_dec(const ushort_t* __restrict__ H, const float* __restrict__ w1,
                                             const float* __restrict__ b1, const float* __restrict__ w2,
                                             const float* __restrict__ b2, float* __restrict__ out){
  __shared__ short w1h[64*72], w1l[64*72];   // [o][c] hi/lo, stride 72 (16B aligned rows)
  __shared__ float w2L[64], b1L[64];
  int t = threadIdx.x, x = blockIdx.x, b = blockIdx.y;
  for (int d=t; d<4096; d+=256){
    int o = d>>6, c = d&63;
    float v = w1[o*64+c];
    ushort_t hi = f2b(v);
    w1h[o*72+c] = (short)hi;
    w1l[o*72+c] = (short)f2b(v - b2f(hi));
  }
  if (t < 64){ w2L[t] = w2[t]; b1L[t] = b1[t]; }
  __syncthreads();

  int w = t >> 6, lane = t & 63;
  int quad = lane >> 4, lcol = lane & 15;
  float bias2 = b2[0];

#pragma unroll
  for (int i=0;i<4;++i){
    int mt = w*4 + i;                        // 0..15 -> y = mt*16+lcol, all < 256 (crop)
    int py = mt*16 + lcol;
    const ushort_t* hp = H + ((size_t)b*NPIX + (size_t)x*PH + py)*64 + quad*8;
    union{uint4 u; short8 s;} a0, a1;
    a0.u = *(const uint4*)hp;
    a1.u = *(const uint4*)(hp + 32);

    float4v acc[4];
#pragma unroll
    for (int n=0;n<4;++n) acc[n] = (float4v){0.f,0.f,0.f,0.f};
#pragma unroll
    for (int n=0;n<4;++n){
      float4v a = acc[n];
      short8 Bh0 = *(const short8*)&w1h[(n*16+lcol)*72 + quad*8];
      short8 Bh1 = *(const short8*)&w1h[(n*16+lcol)*72 + 32 + quad*8];
      short8 Bl0 = *(const short8*)&w1l[(n*16+lcol)*72 + quad*8];
      short8 Bl1 = *(const short8*)&w1l[(n*16+lcol)*72 + 32 + quad*8];
      a = __builtin_amdgcn_mfma_f32_16x16x32_bf16(a0.s, Bh0, a, 0, 0, 0);
      a = __builtin_amdgcn_mfma_f32_16x16x32_bf16(a1.s, Bh1, a, 0, 0, 0);
      a = __builtin_amdgcn_mfma_f32_16x16x32_bf16(a0.s, Bl0, a, 0, 0, 0);
      a = __builtin_amdgcn_mfma_f32_16x16x32_bf16(a1.s, Bl1, a, 0, 0, 0);
      acc[n] = a;
    }

    float s0=0.f, s1=0.f, s2=0.f, s3=0.f;
#pragma unroll
    for (int n=0;n<4;++n){
      int o = n*16 + lcol;
      float wv = w2L[o];
      float bb = b1L[o];
      s0 += wv*gelu_f(acc[n][0] + bb);
      s1 += wv*gelu_f(acc[n][1] + bb);
      s2 += wv*gelu_f(acc[n][2] + bb);
      s3 += wv*gelu_f(acc[n][3] + bb);
    }
#pragma unroll
    for (int m=1;m<16;m<<=1){
      s0 += __shfl_xor(s0, m, 64);
      s1 += __shfl_xor(s1, m, 64);
      s2 += __shfl_xor(s2, m, 64);
      s3 += __shfl_xor(s3, m, 64);
    }
    if (lcol < 4){
      float v = (lcol==0) ? s0 : (lcol==1) ? s1 : (lcol==2) ? s2 : s3;
      out[((size_t)b*256 + x)*256 + mt*16 + quad*4 + lcol] = v + bias2;
    }
  }
}

extern "C" void kernel_launch(void* const* d_in, const int* in_sizes, int n_in,
                              void* d_out, int out_size, void* d_ws, size_t ws_size,
                              hipStream_t stream){
  const float* x    = (const float*)d_in[0];
  const float* liw  = (const float*)d_in[1];
  const float* lib  = (const float*)d_in[2];
  const float* w1   = (const float*)d_in[3];
  const float* w2   = (const float*)d_in[4];
  const float* cw   = (const float*)d_in[5];
  const float* cb   = (const float*)d_in[6];
  const float* gg   = (const float*)d_in[7];
  const float* gb   = (const float*)d_in[8];
  const float* dw1  = (const float*)d_in[9];
  const float* db1  = (const float*)d_in[10];
  const float* dw2  = (const float*)d_in[11];
  const float* db2  = (const float*)d_in[12];
  float* out = (float*)d_out;

  // ws: H 142.7MB bf16 | tmp 69MB fp16 | zB 34.6MB bf16-hi/lo | Xf 4.2MB | oft 4.2MB | tables
  char* p = (char*)d_ws;
  ushort_t* H = (ushort_t*)p; p += (size_t)NBAT*NPIX*64*2;
  half_t* tmp = (half_t*)p; p += (size_t)NBAT*264*32*64*2;
  ushort_t* zB = (ushort_t*)p; p += (size_t)NBAT*264*64*64*2;
  float* Xf   = (float*)p; p += (size_t)NIMG*512*2*4;
  float* oft  = (float*)p; p += (size_t)NIMG*512*2*4;
  float* tFT  = (float*)p; p += 8448*4;
  float* tCT  = (float*)p; p += 8448*4;
  float* tST  = (float*)p; p += 8448*4;
  ushort_t* TWh = (ushort_t*)p; p += 8704*2;
  ushort_t* TWl = (ushort_t*)p; p += 8704*2;
  ushort_t* cwB = (ushort_t*)p; p += 16384*2;
  float2* stats = (float2*)p; p += 64*8;

  k_tables<<<164, 256, 0, stream>>>(tFT, tCT, tST, TWh, TWl, cw, cwB);

  for (int k=0;k<NLAY;++k){
    if (k == 0)
      k_fwd_y0<<<1056, 256, 0, stream>>>(x, liw, lib, tFT, tmp);
    else
      k_fwd_y<<<1056, 256, 0, stream>>>(H, tFT, tmp);
    k_fwd_x<<<dim3(128,16), 256, 0, stream>>>(tmp, tCT, tST, Xf);
    k_mix<<<dim3(64,4), 512, 0, stream>>>(Xf, w1 + (size_t)k*2097152, w2 + (size_t)k*2097152, oft);
    k_stats_spec<<<64, 256, 0, stream>>>(oft, stats);
    k_inv_x<<<1024, 256, 0, stream>>>(oft, tCT, tST, zB, stats, gg + (size_t)k*64);
    k_fused2<<<dim3(264,16), 512, 0, stream>>>(H, zB, cwB + (size_t)k*4096, cb + (size_t)k*64,
                                               gg + (size_t)k*64, gb + (size_t)k*64, stats, TWh, TWl,
                                               x, liw, lib, (k<3)?1:0, (k==0)?1:0);
  }
  k_dec<<<dim3(256,16), 256, 0, stream>>>(H, dw1, db1, dw2, db2, out);
}

// Round 14
// 1304.136 us; speedup vs baseline: 1.1753x; 1.0193x over previous
//
#include <hip/hip_runtime.h>
#include <hip/hip_bf16.h>
#include <math.h>

#define PH   264
#define NPIX (PH*PH)          // 69696
#define NBAT 16
#define NIMG (NBAT*64)        // 1024
#define NLAY 4

typedef unsigned short ushort_t;
typedef unsigned int   uint_t;
typedef _Float16       half_t;
typedef __attribute__((ext_vector_type(8))) short short8;   // 8 bf16 = 4 VGPR (MFMA A/B frag)
typedef __attribute__((ext_vector_type(4))) float float4v;  // MFMA C/D frag

__device__ __forceinline__ float blo(uint_t u){ union{uint_t u; float f;} v; v.u = u << 16;        return v.f; }
__device__ __forceinline__ float bhi(uint_t u){ union{uint_t u; float f;} v; v.u = u & 0xffff0000u; return v.f; }
__device__ __forceinline__ float b2f(ushort_t s){ union{uint_t u; float f;} v; v.u = ((uint_t)s) << 16; return v.f; }
__device__ __forceinline__ ushort_t f2b(float f){
  __hip_bfloat16 h = __float2bfloat16(f);
  union{__hip_bfloat16 h; ushort_t s;} v; v.h = h; return v.s;
}
// tanh-form gelu via sigmoid identity 0.5(1+tanh(z)) = sigma(2z):
//   gelu(v) ~= v / (1 + exp2(-2.3022082*(v + 0.044715 v^3)))
// 8 VALU ops; |err vs exact erf-gelu| ~3e-4 abs — an order below bf16 storage quantization.
__device__ __forceinline__ float gelu_f(float v){
  float x2 = v*v;
  float u  = v*fmaf(0.044715f, x2, 1.0f);
  float e  = __builtin_amdgcn_exp2f(-2.3022082f*u);
  return v*__builtin_amdgcn_rcpf(1.0f + e);
}

// DFT twiddle tables (fp32, exact integer-mod phase) + bf16 hi/lo inv-y twiddle TWg[272][32]
// + bf16 conv weights cwB[L][o][i] (one-time convert; same rounding as per-layer f2b before).
__global__ __launch_bounds__(256) void k_tables(float* __restrict__ tFT, float* __restrict__ tCT,
                                                float* __restrict__ tST,
                                                ushort_t* __restrict__ TWh, ushort_t* __restrict__ TWl,
                                                const float* __restrict__ cw, ushort_t* __restrict__ cwB){
  int idx = blockIdx.x*256 + threadIdx.x;
  const double W0 = 6.283185307179586 / 264.0;
  if (idx < 8448){                       // tFT[y*32+kk]: kk=2k -> cos, 2k+1 -> -sin (e^{-i 2pi k y/264})
    int y = idx >> 5, kk = idx & 31, k = kk >> 1;
    int ph = (k*y) % 264;
    float ang = (float)(W0 * ph), s, c;
    sincosf(ang, &s, &c);
    tFT[idx] = (kk & 1) ? -s : c;
  } else if (idx < 16896){               // tCT/tST[x*32+kxi]: cos/sin(2pi kxe x/264), kxe in [-16,15]
    int d = idx - 8448;
    int x = d >> 5, kxi = d & 31;
    int kxe = (kxi < 16) ? kxi : kxi - 32;
    int ph = ((kxe*x) % 264 + 264) % 264;
    float ang = (float)(W0 * ph), s, c;
    sincosf(ang, &s, &c);
    tCT[d] = c; tST[d] = s;
  } else if (idx < 16896 + 8704){        // TWg[y][kk]: inv-y row; rows >=264 zero (padding m-tile)
    int d = idx - 16896;
    int y = d >> 5, kk = d & 31;
    float v = 0.f;
    if (y < 264){
      if (kk == 0) v = 0.5f;
      else if (kk > 1){
        int j = kk >> 1;
        int ph = (j*y) % 264;
        float ang = (float)(W0 * ph), s, c;
        sincosf(ang, &s, &c);
        v = (kk & 1) ? -s : c;
      }
    }
    ushort_t hi = f2b(v);
    TWh[d] = hi;
    TWl[d] = f2b(v - b2f(hi));
  } else if (idx < 25600 + 16384){       // cwB: all 4 layers, bf16
    int d = idx - 25600;
    cwB[d] = f2b(cw[d]);
  }
}

// fwd DFT along y, LAYER 0: lift computed inline from xin (fp32) — no materialized H read.
__global__ __launch_bounds__(256) void k_fwd_y0(const float* __restrict__ xin, const float* __restrict__ lw,
                                                const float* __restrict__ lb, const float* __restrict__ tFT,
                                                half_t* __restrict__ tmp){
  int t = threadIdx.x;
  int row = blockIdx.x*4 + (t>>6);        // 0..4223 = b*264+x
  int c = t & 63;
  int b = row / 264, x = row - b*264;
  float acc[32];
#pragma unroll
  for (int j=0;j<32;++j) acc[j]=0.f;
  if (x < 256){
    float lwc = lw[c], lbc = lb[c];
    const float* xp = xin + ((size_t)(b*256+x))*256;
    for (int y=0; y<256; ++y){
      float h = lwc*xp[y] + lbc;          // xp[y] wave-uniform broadcast
      const float* fr = tFT + y*32;
#pragma unroll
      for (int j=0;j<32;++j) acc[j] += h*fr[j];
    }
  }
  half_t* op = tmp + (((size_t)row)*32)*64 + c;
#pragma unroll
  for (int j=0;j<32;++j) op[(size_t)j*64] = (half_t)acc[j];
}

// fwd DFT along y (layers 1..3): tmp[b][x][kk][c] = sum_y H[b][x*264+y][c] * tFT[y][kk]
__global__ __launch_bounds__(256) void k_fwd_y(const ushort_t* __restrict__ H, const float* __restrict__ tFT,
                                               half_t* __restrict__ tmp){
  int t = threadIdx.x;
  int row = blockIdx.x*4 + (t>>6);        // 0..4223 = b*264+x
  int c = t & 63;
  int b = row / 264, x = row - b*264;
  const ushort_t* hp = H + ((size_t)b*NPIX + (size_t)x*PH)*64 + c;
  float acc[32];
#pragma unroll
  for (int j=0;j<32;++j) acc[j]=0.f;
  for (int y=0; y<PH; ++y){
    float h = b2f(hp[(size_t)y*64]);
    const float* fr = tFT + y*32;         // wave-uniform
#pragma unroll
    for (int j=0;j<32;++j) acc[j] += h*fr[j];
  }
  half_t* op = tmp + (((size_t)row)*32)*64 + c;
#pragma unroll
  for (int j=0;j<32;++j) op[(size_t)j*64] = (half_t)acc[j];
}

// fwd DFT along x: Xf[img=(b*64+c)][m] = sum_x tmp[b][x][ky-pair][c] * e^{-i..}
__global__ __launch_bounds__(256) void k_fwd_x(const half_t* __restrict__ tmp, const float* __restrict__ tCT,
                                               const float* __restrict__ tST, float* __restrict__ Xf){
  int t = threadIdx.x, b = blockIdx.y;
  int m = blockIdx.x*4 + (t>>6);          // 0..511
  int c = t & 63;
  int kxi = m >> 4, ky = m & 15;
  float xr=0.f, xi=0.f;
  const half_t* base = tmp + ((size_t)b*264*32 + 2*ky)*64 + c;
  for (int x=0; x<PH; ++x){
    float tr = (float)base[(size_t)x*32*64];
    float ti = (float)base[(size_t)x*32*64 + 64];
    float cc = tCT[x*32+kxi], ss = tST[x*32+kxi];   // wave-uniform
    xr += tr*cc + ti*ss;
    xi += ti*cc - tr*ss;
  }
  ((float2*)Xf)[(size_t)(b*64+c)*512 + m] = make_float2(xr, xi);
}

// per-mode 64x64 complex channel mix.
// R12: grid (128 = o*2+mhalf, 8 = 2-batch groups) -> 1024 blocks (was 256 = 1 block/CU,
// 25% occupancy, grid-limited latency hiding). 256 thr; each block one m-half (w1 OR w2),
// 2 batches. Same total W/X traffic, 4 blocks/CU.
__global__ __launch_bounds__(256) void k_mix(const float* __restrict__ Xf, const float* __restrict__ w1,
                                             const float* __restrict__ w2, float* __restrict__ oft){
  int mm = threadIdx.x;
  int o = blockIdx.x >> 1, half = blockIdx.x & 1;
  int m = half*256 + mm;
  int b0 = blockIdx.y*2;
  const float2* X = (const float2*)Xf;
  const float2* W = (const float2*)(half ? w2 : w1);
  float2 acc[2];
  acc[0] = make_float2(0.f,0.f); acc[1] = make_float2(0.f,0.f);
  for (int i=0;i<64;++i){
    float2 w = W[(size_t)(i*64+o)*256 + mm];
#pragma unroll
    for (int b=0;b<2;++b){
      float2 x = X[((size_t)((b0+b)*64+i)*512) + m];
      acc[b].x += x.x*w.x - x.y*w.y;
      acc[b].y += x.x*w.y + x.y*w.x;
    }
  }
  float2* O = (float2*)oft;
#pragma unroll
  for (int b=0;b<2;++b) O[((size_t)((b0+b)*64+o)*512) + m] = acc[b];
}

// GroupNorm stats from oft via Parseval (unchanged)
__global__ __launch_bounds__(256) void k_stats_spec(const float* __restrict__ oft, float2* __restrict__ stats){
  __shared__ float sq[256], s1s[256];
  int bg = blockIdx.x, t = threadIdx.x;
  int b = bg >> 2, g = bg & 3;
  const float2* O = (const float2*)oft;
  float q = 0.f, s1 = 0.f;
  for (int c16=0; c16<16; ++c16){
    const float2* Op = O + (size_t)(b*64 + g*16 + c16)*512;
    for (int m=t; m<512; m+=256){
      if (m & 15){ float2 v = Op[m]; q += 2.f*(v.x*v.x + v.y*v.y); }
    }
  }
  {
    int c16 = t >> 4, j = t & 15;
    const float2* Op = O + (size_t)(b*64 + g*16 + c16)*512;
    if (j == 0){
      float2 a0 = Op[0];
      s1 = a0.x;
      q += a0.x*a0.x;
      float2 h16 = Op[16*16];
      q += 0.5f*(h16.x*h16.x + h16.y*h16.y);
    } else {
      float2 a = Op[j*16];
      float2 bb = Op[(32-j)*16];
      float rr = a.x + bb.x, ii = a.y - bb.y;
      q += 0.5f*(rr*rr + ii*ii);
    }
  }
  sq[t] = q; s1s[t] = s1; __syncthreads();
  for (int st_=128; st_>0; st_>>=1){
    if (t < st_){ sq[t] += sq[t+st_]; s1s[t] += s1s[t+st_]; }
    __syncthreads();
  }
  if (t == 0){
    const float invN = 1.0f/1115136.0f;
    float mu  = s1s[0]*invN;
    float ssq = sq[0]*(1.0f/69696.0f);
    float var = fmaxf(ssq*invN - mu*mu, 0.f);
    stats[bg] = make_float2(mu, 1.0f/sqrtf(var + 1e-5f));
  }
}

// inverse DFT along x, emitting MFMA-B-ready hi/lo bf16 planes premultiplied by
// alpha = rstd*gamma*(2/69696):  zB[((b*264+x)*64 + c)*64 + {0..31:hi, 32..63:lo}]
__global__ __launch_bounds__(256) void k_inv_x(const float* __restrict__ oft, const float* __restrict__ tCT,
                                               const float* __restrict__ tST, ushort_t* __restrict__ zB,
                                               const float2* __restrict__ stats, const float* __restrict__ gg){
  __shared__ float sof[1024];
  int t = threadIdx.x, img = blockIdx.x;
  int b = img >> 6, c = img & 63;
  const float* op = oft + (size_t)img*1024;
  for (int d=t; d<1024; d+=256) sof[d] = op[d];
  __syncthreads();
  float al = stats[b*4 + (c>>4)].y * gg[c] * (2.0f/69696.0f);
  for (int x=t; x<264; x+=256){
    float zr[16], zi[16];
#pragma unroll
    for (int k=0;k<16;++k){ zr[k]=0.f; zi[k]=0.f; }
    for (int kxi=0; kxi<32; ++kxi){
      float cc = tCT[x*32+kxi], ss = tST[x*32+kxi];
#pragma unroll
      for (int ky=0; ky<16; ++ky){
        float orr = sof[(kxi*16+ky)*2], oii = sof[(kxi*16+ky)*2 + 1];
        zr[ky] += orr*cc - oii*ss;
        zi[ky] += oii*cc + orr*ss;
      }
    }
    uint_t wh[16], wl[16];
#pragma unroll
    for (int k=0;k<16;++k){
      float a = zr[k]*al, bb2 = zi[k]*al;
      ushort_t ah = f2b(a),  bh = f2b(bb2);
      ushort_t alo = f2b(a - b2f(ah)), blo_ = f2b(bb2 - b2f(bh));
      wh[k] = (uint_t)ah | ((uint_t)bh << 16);
      wl[k] = (uint_t)alo | ((uint_t)blo_ << 16);
    }
    uint4* dst = (uint4*)(zB + ((size_t)((size_t)(b*264 + x)*64 + c))*64);
#pragma unroll
    for (int q=0;q<4;++q) dst[q]   = ((uint4*)wh)[q];
#pragma unroll
    for (int q=0;q<4;++q) dst[4+q] = ((uint4*)wl)[q];
  }
}

// Row-tile MFMA fused layer: H(new) = gelu( TW·(z·alpha) + H·Wconv + beta ), in place on H.
// grid (264 x-rows, 16 b); 512 thr = 8 waves; wave w owns m-tiles {w, w+8} (16 tiles),
// and TILE 16 (rows 256..263) is split BY N-QUADRANT across waves 0..3 (5 MFMA each,
// single acc16 frag) — balances MFMA 45 vs 40 per wave (was: wave0 did a whole 3rd tile
// while 7 waves waited at the obuf barrier) and cuts AGPR 48 -> 36.
// B operands (zB hi/lo, cwB) PRECOMPUTED in global, staged to LDS; MFMA LDS-fed.
// lay0: A(conv) computed INLINE from xin/lw/lb (lift fused; tile-16 conv input is pad = 0).
// LDS: obuf ALIASES zBs/cws (dead after MFMA loop, barrier-protected).
__global__ __launch_bounds__(512, 4) void k_fused2(ushort_t* __restrict__ H,
                                                const ushort_t* __restrict__ zB,
                                                const ushort_t* __restrict__ cwB,
                                                const float* __restrict__ cb,
                                                const float* __restrict__ gg, const float* __restrict__ gb,
                                                const float2* __restrict__ stats,
                                                const ushort_t* __restrict__ TWh, const ushort_t* __restrict__ TWl,
                                                const float* __restrict__ xin, const float* __restrict__ lw,
                                                const float* __restrict__ lb,
                                                int do_gelu, int lay0){
  __shared__ short smem[9216];               // phase1: zBs[0..4607], cws[4608..9215] (stride 72)
                                             // phase2 (after barrier): obuf[w] = smem + w*1152
  __shared__ float lwL[64], lbL[64];
  short* zBs = smem;
  short* cws = smem + 4608;
  int t = threadIdx.x, b = blockIdx.y, x = blockIdx.x;
  int w = t >> 6, lane = t & 63;
  int quad = lane >> 4, lcol = lane & 15;

  // stage: one uint4 per thread per buffer (8KB each), stride-64 -> stride-72 repack
  {
    int row = t >> 3, q = t & 7;
    const uint4* zsrc = (const uint4*)(zB + ((size_t)(b*264 + x))*64*64);
    *(uint4*)&zBs[row*72 + q*8] = zsrc[t];
    *(uint4*)&cws[row*72 + q*8] = ((const uint4*)cwB)[t];
  }
  if (t < 64){ lwL[t] = lw[t]; lbL[t] = lb[t]; }
  __syncthreads();

  float4v acc[2][4];
#pragma unroll
  for (int si=0;si<2;++si)
#pragma unroll
    for (int n=0;n<4;++n) acc[si][n] = (float4v){0.f,0.f,0.f,0.f};
  float4v acc16 = (float4v){0.f,0.f,0.f,0.f};

#pragma unroll
  for (int si=0;si<2;++si){
    int mt = w + 8*si;                        // 0..15
    int pxl = mt*16 + lcol;                   // 0..255 (< PH always)
    union{uint4 u; short8 s;} a0, a1;
    if (lay0){
      bool in = (x < 256);
      float xv = in ? xin[((size_t)(b*256+x))*256 + pxl] : 0.f;
      uint_t wa[8];
#pragma unroll
      for (int j=0;j<4;++j){
        int ch = quad*8 + 2*j;
        float v0 = in ? (lwL[ch  ]*xv + lbL[ch  ]) : 0.f;
        float v1 = in ? (lwL[ch+1]*xv + lbL[ch+1]) : 0.f;
        wa[j] = (uint_t)f2b(v0) | ((uint_t)f2b(v1) << 16);
        float v2 = in ? (lwL[ch+32]*xv + lbL[ch+32]) : 0.f;
        float v3 = in ? (lwL[ch+33]*xv + lbL[ch+33]) : 0.f;
        wa[4+j] = (uint_t)f2b(v2) | ((uint_t)f2b(v3) << 16);
      }
      a0.u = make_uint4(wa[0], wa[1], wa[2], wa[3]);
      a1.u = make_uint4(wa[4], wa[5], wa[6], wa[7]);
    } else {
      const ushort_t* hp = H + ((size_t)b*NPIX + (size_t)x*PH + pxl)*64 + quad*8;
      a0.u = *(const uint4*)hp;
      a1.u = *(const uint4*)(hp + 32);
    }
    short8 Th = *(const short8*)(TWh + pxl*32 + quad*8);
    short8 Tl = *(const short8*)(TWl + pxl*32 + quad*8);
#pragma unroll
    for (int n=0;n<4;++n){
      float4v a = acc[si][n];
      short8 Bc0 = *(const short8*)&cws[(n*16+lcol)*72 + quad*8];
      short8 Bc1 = *(const short8*)&cws[(n*16+lcol)*72 + 32 + quad*8];
      a = __builtin_amdgcn_mfma_f32_16x16x32_bf16(a0.s, Bc0, a, 0, 0, 0);
      a = __builtin_amdgcn_mfma_f32_16x16x32_bf16(a1.s, Bc1, a, 0, 0, 0);
      short8 Bzh = *(const short8*)&zBs[(n*16+lcol)*72 + quad*8];
      short8 Bzl = *(const short8*)&zBs[(n*16+lcol)*72 + 32 + quad*8];
      a = __builtin_amdgcn_mfma_f32_16x16x32_bf16(Th, Bzh, a, 0, 0, 0);
      a = __builtin_amdgcn_mfma_f32_16x16x32_bf16(Th, Bzl, a, 0, 0, 0);
      a = __builtin_amdgcn_mfma_f32_16x16x32_bf16(Tl, Bzh, a, 0, 0, 0);
      acc[si][n] = a;
    }
  }

  // TILE 16 (rows 256..271; valid 256..263): waves 0..3, n-quadrant = w. Uses zBs/cws (pre-barrier).
  if (w < 4){
    int pxl = 256 + lcol;                     // 256..271
    union{uint4 u; short8 s;} a0, a1;
    a0.u = make_uint4(0,0,0,0); a1.u = make_uint4(0,0,0,0);
    if (!lay0 && pxl < PH){                   // lay0: pad rows of lift are zero
      const ushort_t* hp = H + ((size_t)b*NPIX + (size_t)x*PH + pxl)*64 + quad*8;
      a0.u = *(const uint4*)hp;
      a1.u = *(const uint4*)(hp + 32);
    }
    short8 Th = *(const short8*)(TWh + pxl*32 + quad*8);   // rows >=264 are zero in TW
    short8 Tl = *(const short8*)(TWl + pxl*32 + quad*8);
    int n = w;
    short8 Bc0 = *(const short8*)&cws[(n*16+lcol)*72 + quad*8];
    short8 Bc1 = *(const short8*)&cws[(n*16+lcol)*72 + 32 + quad*8];
    acc16 = __builtin_amdgcn_mfma_f32_16x16x32_bf16(a0.s, Bc0, acc16, 0, 0, 0);
    acc16 = __builtin_amdgcn_mfma_f32_16x16x32_bf16(a1.s, Bc1, acc16, 0, 0, 0);
    short8 Bzh = *(const short8*)&zBs[(n*16+lcol)*72 + quad*8];
    short8 Bzl = *(const short8*)&zBs[(n*16+lcol)*72 + 32 + quad*8];
    acc16 = __builtin_amdgcn_mfma_f32_16x16x32_bf16(Th, Bzh, acc16, 0, 0, 0);
    acc16 = __builtin_amdgcn_mfma_f32_16x16x32_bf16(Th, Bzl, acc16, 0, 0, 0);
    acc16 = __builtin_amdgcn_mfma_f32_16x16x32_bf16(Tl, Bzh, acc16, 0, 0, 0);
  }

  __syncthreads();   // zBs/cws dead for ALL waves -> obuf may alias them

  // epilogue: + (gb - mu*rstd*g + cb), gelu, bounce through per-wave LDS, full-line stores.
  float beta[4];
#pragma unroll
  for (int n=0;n<4;++n){
    int o = n*16 + lcol;
    float2 st = stats[b*4 + n];
    beta[n] = gb[o] - st.x*st.y*gg[o] + cb[o];
  }
  short* ob = smem + w*1152;                 // 16 px * stride 72
#pragma unroll
  for (int si=0;si<2;++si){
    int mt = w + 8*si;
#pragma unroll
    for (int reg=0; reg<4; ++reg){
      int prow = quad*4 + reg;
#pragma unroll
      for (int n=0;n<4;++n){
        float v = acc[si][n][reg] + beta[n];
        if (do_gelu) v = gelu_f(v);
        ob[prow*72 + n*16 + lcol] = (short)f2b(v);
      }
    }
    asm volatile("s_waitcnt lgkmcnt(0)" ::: "memory");   // wave-local: writes visible to own lanes
#pragma unroll
    for (int p=0;p<2;++p){
      int prow2 = p*8 + (lane>>3);
      int c0 = (lane&7)*8;
      int pxl2 = mt*16 + prow2;
      uint4 u = *(const uint4*)&ob[prow2*72 + c0];
      *(uint4*)(H + ((size_t)b*NPIX + (size_t)x*PH + pxl2)*64 + c0) = u;
    }
    asm volatile("" ::: "memory");   // keep next si's obuf writes below these reads
  }
  // tile-16 epilogue: direct 16-lane (32B) stores, rows 256..263, cols w*16+lcol
  if (w < 4){
    int o = w*16 + lcol;
    float2 st = stats[b*4 + w];
    float beta16 = gb[o] - st.x*st.y*gg[o] + cb[o];
#pragma unroll
    for (int reg=0; reg<4; ++reg){
      int pxl = 256 + quad*4 + reg;
      if (pxl < PH){
        float v = acc16[reg] + beta16;
        if (do_gelu) v = gelu_f(v);
        H[((size_t)b*NPIX + (size_t)x*PH + pxl)*64 + o] = f2b(v);
      }
    }
  }
}

// decoder: crop -> dec1 -> gelu -> dec2, MFMA version.
__global__ __launch_bounds__(256) void k_dec(const ushort_t* __restrict__ H, const float* __restrict__ w1,
                                             const float* __restrict__ b1, const float* __restrict__ w2,
                                             const float* __restrict__ b2, float* __restrict__ out){
  __shared__ short w1h[64*72], w1l[64*72];   // [o][c] hi/lo, stride 72 (16B aligned rows)
  __shared__ float w2L[64], b1L[64];
  int t = threadIdx.x, x = blockIdx.x, b = blockIdx.y;
  for (int d=t; d<4096; d+=256){
    int o = d>>6, c = d&63;
    float v = w1[o*64+c];
    ushort_t hi = f2b(v);
    w1h[o*72+c] = (short)hi;
    w1l[o*72+c] = (short)f2b(v - b2f(hi));
  }
  if (t < 64){ w2L[t] = w2[t]; b1L[t] = b1[t]; }
  __syncthreads();

  int w = t >> 6, lane = t & 63;
  int quad = lane >> 4, lcol = lane & 15;
  float bias2 = b2[0];

#pragma unroll
  for (int i=0;i<4;++i){
    int mt = w*4 + i;                        // 0..15 -> y = mt*16+lcol, all < 256 (crop)
    int py = mt*16 + lcol;
    const ushort_t* hp = H + ((size_t)b*NPIX + (size_t)x*PH + py)*64 + quad*8;
    union{uint4 u; short8 s;} a0, a1;
    a0.u = *(const uint4*)hp;
    a1.u = *(const uint4*)(hp + 32);

    float4v acc[4];
#pragma unroll
    for (int n=0;n<4;++n) acc[n] = (float4v){0.f,0.f,0.f,0.f};
#pragma unroll
    for (int n=0;n<4;++n){
      float4v a = acc[n];
      short8 Bh0 = *(const short8*)&w1h[(n*16+lcol)*72 + quad*8];
      short8 Bh1 = *(const short8*)&w1h[(n*16+lcol)*72 + 32 + quad*8];
      short8 Bl0 = *(const short8*)&w1l[(n*16+lcol)*72 + quad*8];
      short8 Bl1 = *(const short8*)&w1l[(n*16+lcol)*72 + 32 + quad*8];
      a = __builtin_amdgcn_mfma_f32_16x16x32_bf16(a0.s, Bh0, a, 0, 0, 0);
      a = __builtin_amdgcn_mfma_f32_16x16x32_bf16(a1.s, Bh1, a, 0, 0, 0);
      a = __builtin_amdgcn_mfma_f32_16x16x32_bf16(a0.s, Bl0, a, 0, 0, 0);
      a = __builtin_amdgcn_mfma_f32_16x16x32_bf16(a1.s, Bl1, a, 0, 0, 0);
      acc[n] = a;
    }

    float s0=0.f, s1=0.f, s2=0.f, s3=0.f;
#pragma unroll
    for (int n=0;n<4;++n){
      int o = n*16 + lcol;
      float wv = w2L[o];
      float bb = b1L[o];
      s0 += wv*gelu_f(acc[n][0] + bb);
      s1 += wv*gelu_f(acc[n][1] + bb);
      s2 += wv*gelu_f(acc[n][2] + bb);
      s3 += wv*gelu_f(acc[n][3] + bb);
    }
#pragma unroll
    for (int m=1;m<16;m<<=1){
      s0 += __shfl_xor(s0, m, 64);
      s1 += __shfl_xor(s1, m, 64);
      s2 += __shfl_xor(s2, m, 64);
      s3 += __shfl_xor(s3, m, 64);
    }
    if (lcol < 4){
      float v = (lcol==0) ? s0 : (lcol==1) ? s1 : (lcol==2) ? s2 : s3;
      out[((size_t)b*256 + x)*256 + mt*16 + quad*4 + lcol] = v + bias2;
    }
  }
}

extern "C" void kernel_launch(void* const* d_in, const int* in_sizes, int n_in,
                              void* d_out, int out_size, void* d_ws, size_t ws_size,
                              hipStream_t stream){
  const float* x    = (const float*)d_in[0];
  const float* liw  = (const float*)d_in[1];
  const float* lib  = (const float*)d_in[2];
  const float* w1   = (const float*)d_in[3];
  const float* w2   = (const float*)d_in[4];
  const float* cw   = (const float*)d_in[5];
  const float* cb   = (const float*)d_in[6];
  const float* gg   = (const float*)d_in[7];
  const float* gb   = (const float*)d_in[8];
  const float* dw1  = (const float*)d_in[9];
  const float* db1  = (const float*)d_in[10];
  const float* dw2  = (const float*)d_in[11];
  const float* db2  = (const float*)d_in[12];
  float* out = (float*)d_out;

  // ws: H 142.7MB bf16 | tmp 69MB fp16 | zB 34.6MB bf16-hi/lo | Xf 4.2MB | oft 4.2MB | tables
  char* p = (char*)d_ws;
  ushort_t* H = (ushort_t*)p; p += (size_t)NBAT*NPIX*64*2;
  half_t* tmp = (half_t*)p; p += (size_t)NBAT*264*32*64*2;
  ushort_t* zB = (ushort_t*)p; p += (size_t)NBAT*264*64*64*2;
  float* Xf   = (float*)p; p += (size_t)NIMG*512*2*4;
  float* oft  = (float*)p; p += (size_t)NIMG*512*2*4;
  float* tFT  = (float*)p; p += 8448*4;
  float* tCT  = (float*)p; p += 8448*4;
  float* tST  = (float*)p; p += 8448*4;
  ushort_t* TWh = (ushort_t*)p; p += 8704*2;
  ushort_t* TWl = (ushort_t*)p; p += 8704*2;
  ushort_t* cwB = (ushort_t*)p; p += 16384*2;
  float2* stats = (float2*)p; p += 64*8;

  k_tables<<<164, 256, 0, stream>>>(tFT, tCT, tST, TWh, TWl, cw, cwB);

  for (int k=0;k<NLAY;++k){
    if (k == 0)
      k_fwd_y0<<<1056, 256, 0, stream>>>(x, liw, lib, tFT, tmp);
    else
      k_fwd_y<<<1056, 256, 0, stream>>>(H, tFT, tmp);
    k_fwd_x<<<dim3(128,16), 256, 0, stream>>>(tmp, tCT, tST, Xf);
    k_mix<<<dim3(128,8), 256, 0, stream>>>(Xf, w1 + (size_t)k*2097152, w2 + (size_t)k*2097152, oft);
    k_stats_spec<<<64, 256, 0, stream>>>(oft, stats);
    k_inv_x<<<1024, 256, 0, stream>>>(oft, tCT, tST, zB, stats, gg + (size_t)k*64);
    k_fused2<<<dim3(264,16), 512, 0, stream>>>(H, zB, cwB + (size_t)k*4096, cb + (size_t)k*64,
                                               gg + (size_t)k*64, gb + (size_t)k*64, stats, TWh, TWl,
                                               x, liw, lib, (k<3)?1:0, (k==0)?1:0);
  }
  k_dec<<<dim3(256,16), 256, 0, stream>>>(H, dw1, db1, dw2, db2, out);
}